// Round 3
// baseline (17260.776 us; speedup 1.0000x reference)
//
#include <hip/hip_runtime.h>
#include <hip/hip_bf16.h>
#include <math.h>

namespace {

constexpr int Bb   = 16;
constexpr int Cc   = 128;
constexpr int Tt   = 294;
constexpr int Vv   = 25;
constexpr int TV   = Tt * Vv;        // 7350
constexpr int NPOS = Bb * TV;        // 117600
constexpr int INNER = 512;
constexpr int HID   = 512;
constexpr int NH    = 8;
constexpr int DH    = 64;
constexpr int Pp    = 7;             // local patch
constexpr int Kk    = 7;             // global kv stride
constexpr int NT    = 42;            // T / P
constexpr int TK    = 42;            // T / K
constexpr float EPS   = 1e-5f;
constexpr float SCALE = 0.125f;      // 64^-0.5
constexpr int FR = 20;               // ff rows per block (117600 = 20*5880)
constexpr int QKVP = 3 * INNER + 2;  // padded qkv stride in k_local

// ---------- batched transpose: src (M x N) -> dst (N x M), z = batch ----------
__global__ __launch_bounds__(256) void k_transpose(const float* __restrict__ src,
                                                   float* __restrict__ dst,
                                                   int M, int N) {
  __shared__ float tile[32][33];
  size_t off = (size_t)blockIdx.z * (size_t)M * (size_t)N;
  src += off; dst += off;
  int bx = blockIdx.x * 32, by = blockIdx.y * 32;
  int tx = threadIdx.x, ty = threadIdx.y;   // (32, 8)
#pragma unroll
  for (int r = 0; r < 4; ++r) {
    int row = by + ty + r * 8, col = bx + tx;
    if (row < M && col < N) tile[ty + r * 8][tx] = src[(size_t)row * N + col];
  }
  __syncthreads();
#pragma unroll
  for (int r = 0; r < 4; ++r) {
    int row = bx + ty + r * 8, col = by + tx;
    if (row < N && col < M) dst[(size_t)row * M + col] = tile[tx][ty + r * 8];
  }
}

// ---------- per-position LN stats over C (mean, rstd) ----------
__global__ __launch_bounds__(256) void k_stats(const float* __restrict__ xT,
                                               float* __restrict__ mean,
                                               float* __restrict__ rstd) {
  int row  = blockIdx.x * 4 + (threadIdx.x >> 6);
  int lane = threadIdx.x & 63;
  const float* p = xT + (size_t)row * Cc;
  float a = p[lane], b = p[lane + 64];
  float s = a + b, ss = a * a + b * b;
#pragma unroll
  for (int off = 32; off; off >>= 1) {
    s  += __shfl_xor(s, off);
    ss += __shfl_xor(ss, off);
  }
  if (lane == 0) {
    float m = s * (1.0f / Cc);
    mean[row] = m;
    rstd[row] = rsqrtf(ss * (1.0f / Cc) - m * m + EPS);
  }
}

// ---------- fused local attention: one block per (b, patch, v) ----------
__global__ __launch_bounds__(256) void k_local(float* __restrict__ xT,
                                               const float* __restrict__ mean,
                                               const float* __restrict__ rstd,
                                               const float* __restrict__ g,
                                               const float* __restrict__ be,
                                               const float* __restrict__ wq,
                                               const float* __restrict__ wkv,
                                               const float* __restrict__ wo,
                                               const float* __restrict__ bo) {
  __shared__ float xs[Pp][Cc];          // original rows (residual)
  __shared__ float xn[Pp][Cc];          // normed rows
  __shared__ float qkv[Pp][QKVP];       // q | k | v (padded stride); q reused for o
  __shared__ float att[NH][Pp][Pp];
  __shared__ float pbuf[2][Pp][Cc];     // proj partials

  int bid = blockIdx.x;
  int v   = bid % Vv;
  int ntb = (bid / Vv) % NT;
  int b   = bid / (Vv * NT);
  int tid = threadIdx.x;
  int t0  = ntb * Pp;

  for (int e = tid; e < Pp * Cc; e += 256) {
    int p = e >> 7, c = e & 127;
    int row = (b * Tt + t0 + p) * Vv + v;
    float val = xT[(size_t)row * Cc + c];
    xs[p][c] = val;
    xn[p][c] = (val - mean[row]) * rstd[row] * g[c] + be[c];
  }
  __syncthreads();

  // q,k,v = xn @ [wq | wkv]
  for (int col = tid; col < 3 * INNER; col += 256) {
    const float* wp; int stride, ccol;
    if (col < INNER) { wp = wq;  stride = INNER;     ccol = col; }
    else             { wp = wkv; stride = 2 * INNER; ccol = col - INNER; }
    float acc[Pp];
#pragma unroll
    for (int p = 0; p < Pp; ++p) acc[p] = 0.f;
    for (int c = 0; c < Cc; ++c) {
      float wv = wp[(size_t)c * stride + ccol];
#pragma unroll
      for (int p = 0; p < Pp; ++p) acc[p] += xn[p][c] * wv;
    }
#pragma unroll
    for (int p = 0; p < Pp; ++p) qkv[p][col] = acc[p];
  }
  __syncthreads();

  // dots
  for (int e = tid; e < NH * Pp * Pp; e += 256) {
    int h = e / (Pp * Pp), r = e % (Pp * Pp);
    int i = r / Pp, j = r % Pp;
    float acc = 0.f;
#pragma unroll 16
    for (int d = 0; d < DH; ++d)
      acc += qkv[i][h * DH + d] * qkv[j][INNER + h * DH + d];
    att[h][i][j] = acc * SCALE;
  }
  __syncthreads();

  // softmax rows (56 rows of 7)
  for (int rr = tid; rr < NH * Pp; rr += 256) {
    int h = rr / Pp, i = rr % Pp;
    float mx = att[h][i][0];
#pragma unroll
    for (int j = 1; j < Pp; ++j) mx = fmaxf(mx, att[h][i][j]);
    float ev[Pp], sum = 0.f;
#pragma unroll
    for (int j = 0; j < Pp; ++j) { ev[j] = expf(att[h][i][j] - mx); sum += ev[j]; }
    float inv = 1.0f / sum;
#pragma unroll
    for (int j = 0; j < Pp; ++j) att[h][i][j] = ev[j] * inv;
  }
  __syncthreads();

  // o = att @ v  (overwrite q region)
  for (int e = tid; e < Pp * INNER; e += 256) {
    int p = e >> 9, i = e & 511, h = i >> 6;
    float acc = 0.f;
#pragma unroll
    for (int j = 0; j < Pp; ++j) acc += att[h][p][j] * qkv[j][2 * INNER + i];
    qkv[p][i] = acc;
  }
  __syncthreads();

  // proj: split i-range over two half-blocks, partials into pbuf
  {
    int co = tid & 127, ih = tid >> 7;
    float acc[Pp];
#pragma unroll
    for (int p = 0; p < Pp; ++p) acc[p] = 0.f;
    for (int i = ih * 256; i < ih * 256 + 256; ++i) {
      float wv = wo[(size_t)i * Cc + co];
#pragma unroll
      for (int p = 0; p < Pp; ++p) acc[p] += qkv[p][i] * wv;
    }
#pragma unroll
    for (int p = 0; p < Pp; ++p) pbuf[ih][p][co] = acc[p];
  }
  __syncthreads();
  for (int e = tid; e < Pp * Cc; e += 256) {
    int p = e >> 7, co = e & 127;
    int row = (b * Tt + t0 + p) * Vv + v;
    float s = bo[co] + xs[p][co] + pbuf[0][p][co] + pbuf[1][p][co];
    xT[(size_t)row * Cc + co] = s;
  }
}

// ---------- fused feed-forward: FR rows per block ----------
__global__ __launch_bounds__(256) void k_ff(float* __restrict__ xT,
                                            const float* __restrict__ mean,
                                            const float* __restrict__ rstd,
                                            const float* __restrict__ g,
                                            const float* __restrict__ be,
                                            const float* __restrict__ w1,
                                            const float* __restrict__ b1,
                                            const float* __restrict__ w2,
                                            const float* __restrict__ b2) {
  __shared__ float xn[FR][Cc];
  __shared__ float hb[FR][HID];   // hidden; later reused for partials
  int tid = threadIdx.x;
  int row0 = blockIdx.x * FR;

  for (int e = tid; e < FR * Cc; e += 256) {
    int r = e >> 7, c = e & 127;
    int row = row0 + r;
    float val = xT[(size_t)row * Cc + c];
    xn[r][c] = (val - mean[row]) * rstd[row] * g[c] + be[c];
  }
  __syncthreads();

  for (int col = tid; col < HID; col += 256) {
    float acc[FR];
#pragma unroll
    for (int r = 0; r < FR; ++r) acc[r] = 0.f;
    for (int c = 0; c < Cc; ++c) {
      float wv = w1[(size_t)c * HID + col];
#pragma unroll
      for (int r = 0; r < FR; ++r) acc[r] += xn[r][c] * wv;
    }
    float bb = b1[col];
#pragma unroll
    for (int r = 0; r < FR; ++r) {
      float xv = acc[r] + bb;
      hb[r][col] = 0.5f * xv * (1.0f + erff(xv * 0.70710678118654752f));
    }
  }
  __syncthreads();

  {
    int co = tid & 127, ih = tid >> 7;
    float acc[FR];
#pragma unroll
    for (int r = 0; r < FR; ++r) acc[r] = 0.f;
    for (int j = ih * 256; j < ih * 256 + 256; ++j) {
      float wv = w2[(size_t)j * Cc + co];
#pragma unroll
      for (int r = 0; r < FR; ++r) acc[r] += hb[r][j] * wv;
    }
    __syncthreads();   // all hb reads done before overwrite
    float* part = &hb[0][0];
#pragma unroll
    for (int r = 0; r < FR; ++r) part[ih * (FR * Cc) + r * Cc + co] = acc[r];
  }
  __syncthreads();
  {
    const float* part = &hb[0][0];
    for (int e = tid; e < FR * Cc; e += 256) {
      int r = e >> 7, co = e & 127;
      int row = row0 + r;
      float s = b2[co] + xT[(size_t)row * Cc + co] + part[r * Cc + co] + part[FR * Cc + r * Cc + co];
      xT[(size_t)row * Cc + co] = s;
    }
  }
}

// ---------- global attention: kv blocked conv, one block per (b, v, third) ----------
__global__ __launch_bounds__(256) void k_gkv(const float* __restrict__ xT,
                                             const float* __restrict__ mean,
                                             const float* __restrict__ rstd,
                                             const float* __restrict__ g,
                                             const float* __restrict__ be,
                                             const float* __restrict__ wkv,
                                             float* __restrict__ kvg) {
  __shared__ float xs[98][Cc];   // 98 = 14 j-blocks * 7
  int bid = blockIdx.x;
  int jh = bid % 3;
  int v  = (bid / 3) % Vv;
  int b  = bid / (3 * Vv);
  int tid = threadIdx.x;
  int tl0 = jh * 98;

  for (int e = tid; e < 98 * Cc; e += 256) {
    int r = e >> 7, c = e & 127;
    int row = (b * Tt + tl0 + r) * Vv + v;
    float val = xT[(size_t)row * Cc + c];
    xs[r][c] = (val - mean[row]) * rstd[row] * g[c] + be[c];
  }
  __syncthreads();

  int j0 = jh * 14;
  for (int col = tid; col < 2 * INNER; col += 256) {
    float acc[14];
#pragma unroll
    for (int j = 0; j < 14; ++j) acc[j] = 0.f;
    for (int kk = 0; kk < Kk; ++kk) {
      for (int c = 0; c < Cc; ++c) {
        float wv = wkv[((size_t)c * Kk + kk) * (2 * INNER) + col];
#pragma unroll
        for (int j = 0; j < 14; ++j) acc[j] += xs[j * 7 + kk][c] * wv;
      }
    }
#pragma unroll
    for (int j = 0; j < 14; ++j)
      kvg[((size_t)(b * Vv + v) * TK + j0 + j) * (2 * INNER) + col] = acc[j];
  }
}

// ---------- global attention: fused q + attn + proj, conflict-free rewrite ----------
// per block: (b, v, t-tile of 32). q per-head-padded bf16 LDS -> f32 regs;
// dots/PV entirely in regs with float4 global k/v; proj row-split, no pbuf.
__global__ __launch_bounds__(256) void k_gattn(float* __restrict__ xT,
                                               const float* __restrict__ mean,
                                               const float* __restrict__ rstd,
                                               const float* __restrict__ g,
                                               const float* __restrict__ be,
                                               const float* __restrict__ wq,
                                               const float* __restrict__ kvg,
                                               const float* __restrict__ wo,
                                               const float* __restrict__ bo) {
  constexpr int TTt = 32;
  constexpr int QS  = 68;   // bf16 stride per (r,h) row; 34 words -> bank = 2*lane+w
  // union: [xn f32 32x132 | qp bf16 32*8*68]  then  [op bf16 32*8*68 ...]
  __shared__ __align__(16) char smem[16896 + 32 * 8 * QS * 2];
  float* xn = (float*)smem;                                   // [32][132]
  __hip_bfloat16* qp = (__hip_bfloat16*)(smem + 16896);       // [32*8][68]
  uint32_t* qpw = (uint32_t*)qp;
  __hip_bfloat16* op = (__hip_bfloat16*)smem;                 // [32*8][68] (reuses xn+qp)
  uint32_t* opw = (uint32_t*)op;

  int bid = blockIdx.x;
  int tt = bid % 10;
  int v  = (bid / 10) % Vv;
  int b  = bid / (10 * Vv);
  int tid = threadIdx.x;
  int t0 = tt * TTt;
  int nT = (Tt - t0 < TTt) ? (Tt - t0) : TTt;   // 32 or 6

  // LN into xn (rows >= nT zeroed)
  for (int e = tid; e < TTt * Cc; e += 256) {
    int r = e >> 7, c = e & 127;
    float val = 0.f;
    if (r < nT) {
      int row = (b * Tt + t0 + r) * Vv + v;
      float xv = xT[(size_t)row * Cc + c];
      val = (xv - mean[row]) * rstd[row] * g[c] + be[c];
    }
    xn[r * 132 + c] = val;
  }
  __syncthreads();

  // q = xn @ wq -> padded bf16 LDS
#pragma unroll
  for (int pass = 0; pass < 2; ++pass) {
    int col = tid + pass * 256;
    int h = col >> 6, d = col & 63;
    float acc[TTt];
#pragma unroll
    for (int r = 0; r < TTt; ++r) acc[r] = 0.f;
    for (int c = 0; c < Cc; ++c) {
      float wv = wq[(size_t)c * INNER + col];
#pragma unroll
      for (int r = 0; r < TTt; ++r) acc[r] += xn[r * 132 + c] * wv;
    }
#pragma unroll
    for (int r = 0; r < TTt; ++r)
      qp[(r * 8 + h) * QS + d] = __float2bfloat16(acc[r]);
  }
  __syncthreads();

  // load q row into registers (f32)
  int r = tid >> 3, h = tid & 7;
  float q[DH];
  {
    const uint32_t* qrow = qpw + (r * 8 + h) * (QS / 2);
#pragma unroll
    for (int w = 0; w < 32; ++w) {
      uint32_t u = qrow[w];
      q[2 * w]     = __uint_as_float(u << 16);
      q[2 * w + 1] = __uint_as_float(u & 0xffff0000u);
    }
  }
  __syncthreads();   // after this, xn/qp regions are dead; op region is free

  const float* kb = kvg + (size_t)(b * Vv + v) * TK * (2 * INNER) + h * DH;
  bool act = (r < nT);
  float s[TK];
  if (act) {
#pragma unroll
    for (int j = 0; j < TK; ++j) {
      const float4* k4 = (const float4*)(kb + (size_t)j * (2 * INNER));
      float acc = 0.f;
#pragma unroll
      for (int w = 0; w < 16; ++w) {
        float4 kk = k4[w];
        acc += q[4 * w] * kk.x + q[4 * w + 1] * kk.y + q[4 * w + 2] * kk.z + q[4 * w + 3] * kk.w;
      }
      s[j] = acc * SCALE;
    }
    float mx = s[0];
#pragma unroll
    for (int j = 1; j < TK; ++j) mx = fmaxf(mx, s[j]);
    float sum = 0.f;
#pragma unroll
    for (int j = 0; j < TK; ++j) { s[j] = expf(s[j] - mx); sum += s[j]; }
    float inv = 1.0f / sum;
#pragma unroll
    for (int j = 0; j < TK; ++j) s[j] *= inv;
  }

  float o[DH];
#pragma unroll
  for (int d = 0; d < DH; ++d) o[d] = 0.f;
  if (act) {
#pragma unroll
    for (int j = 0; j < TK; ++j) {
      float wj = s[j];
      const float4* v4 = (const float4*)(kb + (size_t)j * (2 * INNER) + INNER);
#pragma unroll
      for (int w = 0; w < 16; ++w) {
        float4 vv = v4[w];
        o[4 * w]     += wj * vv.x;
        o[4 * w + 1] += wj * vv.y;
        o[4 * w + 2] += wj * vv.z;
        o[4 * w + 3] += wj * vv.w;
      }
    }
  }

  // write o (bf16 packed pairs) to padded LDS (zeros for inactive rows)
  {
    uint32_t* orow = opw + (r * 8 + h) * (QS / 2);
#pragma unroll
    for (int w = 0; w < 32; ++w) {
      __hip_bfloat16 b0 = __float2bfloat16(o[2 * w]);
      __hip_bfloat16 b1 = __float2bfloat16(o[2 * w + 1]);
      uint32_t u = (uint32_t)(*(uint16_t*)&b0) | ((uint32_t)(*(uint16_t*)&b1) << 16);
      orow[w] = u;
    }
  }
  __syncthreads();

  // proj + residual: half-blocks own 16 rows each, full i-sum (no partial buf)
  {
    int co = tid & 127, ih = tid >> 7;
    int r0 = ih * 16;
    float acc[16];
#pragma unroll
    for (int k = 0; k < 16; ++k) acc[k] = 0.f;
    float bco = bo[co];
    for (int ip = 0; ip < 256; ++ip) {          // i = 2*ip, 2*ip+1
      int h2 = ip >> 5, dw = ip & 31;
      float wv0 = wo[(size_t)(2 * ip) * Cc + co];
      float wv1 = wo[(size_t)(2 * ip + 1) * Cc + co];
#pragma unroll
      for (int k = 0; k < 16; ++k) {
        uint32_t u = opw[((r0 + k) * 8 + h2) * (QS / 2) + dw];
        acc[k] += __uint_as_float(u << 16) * wv0
                + __uint_as_float(u & 0xffff0000u) * wv1;
      }
    }
#pragma unroll
    for (int k = 0; k < 16; ++k) {
      int rr = r0 + k;
      if (rr < nT) {
        int row = (b * Tt + t0 + rr) * Vv + v;
        float old = xT[(size_t)row * Cc + co];
        xT[(size_t)row * Cc + co] = bco + old + acc[k];
      }
    }
  }
}

}  // namespace

extern "C" void kernel_launch(void* const* d_in, const int* in_sizes, int n_in,
                              void* d_out, int out_size, void* d_ws, size_t ws_size,
                              hipStream_t stream) {
  const float* x      = (const float*)d_in[0];
  const float* ln1_g  = (const float*)d_in[1];
  const float* ln1_b  = (const float*)d_in[2];
  const float* la_wq  = (const float*)d_in[3];
  const float* la_wkv = (const float*)d_in[4];
  const float* la_wo  = (const float*)d_in[5];
  const float* la_bo  = (const float*)d_in[6];
  const float* ln2_g  = (const float*)d_in[7];
  const float* ln2_b  = (const float*)d_in[8];
  const float* ff1_w1 = (const float*)d_in[9];
  const float* ff1_b1 = (const float*)d_in[10];
  const float* ff1_w2 = (const float*)d_in[11];
  const float* ff1_b2 = (const float*)d_in[12];
  const float* ln3_g  = (const float*)d_in[13];
  const float* ln3_b  = (const float*)d_in[14];
  const float* ga_wq  = (const float*)d_in[15];
  const float* ga_wkv = (const float*)d_in[16];
  const float* ga_wo  = (const float*)d_in[17];
  const float* ga_bo  = (const float*)d_in[18];
  const float* ln4_g  = (const float*)d_in[19];
  const float* ln4_b  = (const float*)d_in[20];
  const float* ff2_w1 = (const float*)d_in[21];
  const float* ff2_b1 = (const float*)d_in[22];
  const float* ff2_w2 = (const float*)d_in[23];
  const float* ff2_b2 = (const float*)d_in[24];

  float* xT   = (float*)d_ws;                       // NPOS*Cc
  float* mean = xT + (size_t)NPOS * Cc;             // NPOS
  float* rstd = mean + NPOS;                        // NPOS
  float* kvg  = rstd + NPOS;                        // Bb*Vv*TK*1024

  dim3 blk2(32, 8);
  hipLaunchKernelGGL(k_transpose, dim3((TV + 31) / 32, (Cc + 31) / 32, Bb), blk2, 0, stream,
                     x, xT, Cc, TV);

  for (int i = 0; i < 2; ++i) {
    hipLaunchKernelGGL(k_stats, dim3(NPOS / 4), dim3(256), 0, stream, xT, mean, rstd);
    hipLaunchKernelGGL(k_local, dim3(Bb * NT * Vv), dim3(256), 0, stream,
                       xT, mean, rstd, ln1_g + i * Cc, ln1_b + i * Cc,
                       la_wq + (size_t)i * Cc * INNER, la_wkv + (size_t)i * Cc * 2 * INNER,
                       la_wo + (size_t)i * INNER * Cc, la_bo + i * Cc);

    hipLaunchKernelGGL(k_stats, dim3(NPOS / 4), dim3(256), 0, stream, xT, mean, rstd);
    hipLaunchKernelGGL(k_ff, dim3(NPOS / FR), dim3(256), 0, stream,
                       xT, mean, rstd, ln2_g + i * Cc, ln2_b + i * Cc,
                       ff1_w1 + (size_t)i * Cc * HID, ff1_b1 + i * HID,
                       ff1_w2 + (size_t)i * HID * Cc, ff1_b2 + i * Cc);

    hipLaunchKernelGGL(k_stats, dim3(NPOS / 4), dim3(256), 0, stream, xT, mean, rstd);
    hipLaunchKernelGGL(k_gkv, dim3(Bb * Vv * 3), dim3(256), 0, stream,
                       xT, mean, rstd, ln3_g + i * Cc, ln3_b + i * Cc,
                       ga_wkv + (size_t)i * Cc * Kk * 2 * INNER, kvg);
    hipLaunchKernelGGL(k_gattn, dim3(Bb * Vv * 10), dim3(256), 0, stream,
                       xT, mean, rstd, ln3_g + i * Cc, ln3_b + i * Cc,
                       ga_wq + (size_t)i * Cc * INNER, kvg,
                       ga_wo + (size_t)i * INNER * Cc, ga_bo + i * Cc);

    hipLaunchKernelGGL(k_stats, dim3(NPOS / 4), dim3(256), 0, stream, xT, mean, rstd);
    hipLaunchKernelGGL(k_ff, dim3(NPOS / FR), dim3(256), 0, stream,
                       xT, mean, rstd, ln4_g + i * Cc, ln4_b + i * Cc,
                       ff2_w1 + (size_t)i * Cc * HID, ff2_b1 + i * HID,
                       ff2_w2 + (size_t)i * HID * Cc, ff2_b2 + i * Cc);
  }

  hipLaunchKernelGGL(k_transpose, dim3((Cc + 31) / 32, (TV + 31) / 32, Bb), blk2, 0, stream,
                     xT, (float*)d_out, TV, Cc);
}

// Round 4
// 5711.695 us; speedup vs baseline: 3.0220x; 3.0220x over previous
//
#include <hip/hip_runtime.h>
#include <hip/hip_bf16.h>
#include <math.h>

namespace {

constexpr int Bb   = 16;
constexpr int Cc   = 128;
constexpr int Tt   = 294;
constexpr int Vv   = 25;
constexpr int TV   = Tt * Vv;        // 7350
constexpr int NPOS = Bb * TV;        // 117600
constexpr int INNER = 512;
constexpr int HID   = 512;
constexpr int NH    = 8;
constexpr int DH    = 64;
constexpr int Pp    = 7;
constexpr int Kk    = 7;
constexpr int NT    = 42;
constexpr int TK    = 42;            // T / K
constexpr int NKV   = Bb * TK * Vv;  // 16800 kv rows
constexpr float EPS   = 1e-5f;
constexpr float SCALE = 0.125f;
constexpr int QKVP = 3 * INNER + 2;

typedef __attribute__((ext_vector_type(8))) short bf16x8;
typedef __attribute__((ext_vector_type(4))) float f32x4;

__device__ inline float bflo(uint32_t u) { union { float f; uint32_t i; } x; x.i = u << 16; return x.f; }
__device__ inline float bfhi(uint32_t u) { union { float f; uint32_t i; } x; x.i = u & 0xffff0000u; return x.f; }
__device__ inline unsigned short f2bf(float f) {
  union { float f; uint32_t i; } x; x.f = f;
  uint32_t r = x.i + 0x7fffu + ((x.i >> 16) & 1u);
  return (unsigned short)(r >> 16);
}

// packed-weight offsets (elements), per-layer stride
constexpr int OFF_FF1W1 = 0;
constexpr int OFF_FF1W2 = 65536;
constexpr int OFF_FF2W1 = 131072;
constexpr int OFF_FF2W2 = 196608;
constexpr int OFF_GAWQ  = 262144;
constexpr int OFF_GAWO  = 327680;
constexpr int OFF_GAWKV = 393216;    // 7 * 131072
constexpr size_t LPK = 1310720;      // per-layer packed elements

// ---------- pack fp32 B[K x N] -> bf16 MFMA fragment layout ----------
// dst[((nt*nks+ks)*64 + lane)*8 + j] = B[ks*32 + (lane>>4)*8 + j][nt*16 + (lane&15)]
__global__ __launch_bounds__(64) void k_pack(const float* __restrict__ src,
                                             unsigned short* __restrict__ dst,
                                             int nks, int rowStride,
                                             size_t srcLayerStride, size_t dstLayerStride,
                                             int kkSrcOff, int kkDstOff) {
  int bid = blockIdx.x;
  int nt = bid / nks, ks = bid % nks;
  int l = threadIdx.x;
  const float* s = src + (size_t)blockIdx.z * srcLayerStride + (size_t)blockIdx.y * kkSrcOff;
  unsigned short* d = dst + (size_t)blockIdx.z * dstLayerStride + (size_t)blockIdx.y * kkDstOff
                      + ((size_t)bid * 64 + l) * 8;
  int rowb = ks * 32 + (l >> 4) * 8, col = nt * 16 + (l & 15);
  unsigned short tmp[8];
#pragma unroll
  for (int j = 0; j < 8; ++j) tmp[j] = f2bf(s[(size_t)(rowb + j) * rowStride + col]);
#pragma unroll
  for (int j = 0; j < 8; ++j) d[j] = tmp[j];
}

// ---------- batched transpose ----------
__global__ __launch_bounds__(256) void k_transpose(const float* __restrict__ src,
                                                   float* __restrict__ dst,
                                                   int M, int N) {
  __shared__ float tile[32][33];
  size_t off = (size_t)blockIdx.z * (size_t)M * (size_t)N;
  src += off; dst += off;
  int bx = blockIdx.x * 32, by = blockIdx.y * 32;
  int tx = threadIdx.x, ty = threadIdx.y;
#pragma unroll
  for (int r = 0; r < 4; ++r) {
    int row = by + ty + r * 8, col = bx + tx;
    if (row < M && col < N) tile[ty + r * 8][tx] = src[(size_t)row * N + col];
  }
  __syncthreads();
#pragma unroll
  for (int r = 0; r < 4; ++r) {
    int row = bx + ty + r * 8, col = by + tx;
    if (row < N && col < M) dst[(size_t)row * M + col] = tile[tx][ty + r * 8];
  }
}

// ---------- per-position LN stats ----------
__global__ __launch_bounds__(256) void k_stats(const float* __restrict__ xT,
                                               float* __restrict__ mean,
                                               float* __restrict__ rstd) {
  int row  = blockIdx.x * 4 + (threadIdx.x >> 6);
  int lane = threadIdx.x & 63;
  const float* p = xT + (size_t)row * Cc;
  float a = p[lane], b = p[lane + 64];
  float s = a + b, ss = a * a + b * b;
#pragma unroll
  for (int off = 32; off; off >>= 1) {
    s  += __shfl_xor(s, off);
    ss += __shfl_xor(ss, off);
  }
  if (lane == 0) {
    float m = s * (1.0f / Cc);
    mean[row] = m;
    rstd[row] = rsqrtf(ss * (1.0f / Cc) - m * m + EPS);
  }
}

// ---------- fused local attention (unchanged, known-good) ----------
__global__ __launch_bounds__(256) void k_local(float* __restrict__ xT,
                                               const float* __restrict__ mean,
                                               const float* __restrict__ rstd,
                                               const float* __restrict__ g,
                                               const float* __restrict__ be,
                                               const float* __restrict__ wq,
                                               const float* __restrict__ wkv,
                                               const float* __restrict__ wo,
                                               const float* __restrict__ bo) {
  __shared__ float xs[Pp][Cc];
  __shared__ float xn[Pp][Cc];
  __shared__ float qkv[Pp][QKVP];
  __shared__ float att[NH][Pp][Pp];
  __shared__ float pbuf[2][Pp][Cc];

  int bid = blockIdx.x;
  int v   = bid % Vv;
  int ntb = (bid / Vv) % NT;
  int b   = bid / (Vv * NT);
  int tid = threadIdx.x;
  int t0  = ntb * Pp;

  for (int e = tid; e < Pp * Cc; e += 256) {
    int p = e >> 7, c = e & 127;
    int row = (b * Tt + t0 + p) * Vv + v;
    float val = xT[(size_t)row * Cc + c];
    xs[p][c] = val;
    xn[p][c] = (val - mean[row]) * rstd[row] * g[c] + be[c];
  }
  __syncthreads();

  for (int col = tid; col < 3 * INNER; col += 256) {
    const float* wp; int stride, ccol;
    if (col < INNER) { wp = wq;  stride = INNER;     ccol = col; }
    else             { wp = wkv; stride = 2 * INNER; ccol = col - INNER; }
    float acc[Pp];
#pragma unroll
    for (int p = 0; p < Pp; ++p) acc[p] = 0.f;
    for (int c = 0; c < Cc; ++c) {
      float wv = wp[(size_t)c * stride + ccol];
#pragma unroll
      for (int p = 0; p < Pp; ++p) acc[p] += xn[p][c] * wv;
    }
#pragma unroll
    for (int p = 0; p < Pp; ++p) qkv[p][col] = acc[p];
  }
  __syncthreads();

  for (int e = tid; e < NH * Pp * Pp; e += 256) {
    int h = e / (Pp * Pp), r = e % (Pp * Pp);
    int i = r / Pp, j = r % Pp;
    float acc = 0.f;
#pragma unroll 16
    for (int d = 0; d < DH; ++d)
      acc += qkv[i][h * DH + d] * qkv[j][INNER + h * DH + d];
    att[h][i][j] = acc * SCALE;
  }
  __syncthreads();

  for (int rr = tid; rr < NH * Pp; rr += 256) {
    int h = rr / Pp, i = rr % Pp;
    float mx = att[h][i][0];
#pragma unroll
    for (int j = 1; j < Pp; ++j) mx = fmaxf(mx, att[h][i][j]);
    float ev[Pp], sum = 0.f;
#pragma unroll
    for (int j = 0; j < Pp; ++j) { ev[j] = expf(att[h][i][j] - mx); sum += ev[j]; }
    float inv = 1.0f / sum;
#pragma unroll
    for (int j = 0; j < Pp; ++j) att[h][i][j] = ev[j] * inv;
  }
  __syncthreads();

  for (int e = tid; e < Pp * INNER; e += 256) {
    int p = e >> 9, i = e & 511, h = i >> 6;
    float acc = 0.f;
#pragma unroll
    for (int j = 0; j < Pp; ++j) acc += att[h][p][j] * qkv[j][2 * INNER + i];
    qkv[p][i] = acc;
  }
  __syncthreads();

  {
    int co = tid & 127, ih = tid >> 7;
    float acc[Pp];
#pragma unroll
    for (int p = 0; p < Pp; ++p) acc[p] = 0.f;
    for (int i = ih * 256; i < ih * 256 + 256; ++i) {
      float wv = wo[(size_t)i * Cc + co];
#pragma unroll
      for (int p = 0; p < Pp; ++p) acc[p] += qkv[p][i] * wv;
    }
#pragma unroll
    for (int p = 0; p < Pp; ++p) pbuf[ih][p][co] = acc[p];
  }
  __syncthreads();
  for (int e = tid; e < Pp * Cc; e += 256) {
    int p = e >> 7, co = e & 127;
    int row = (b * Tt + t0 + p) * Vv + v;
    float s = bo[co] + xs[p][co] + pbuf[0][p][co] + pbuf[1][p][co];
    xT[(size_t)row * Cc + co] = s;
  }
}

// ---------- MFMA fused feed-forward: 32 rows/block ----------
__global__ __launch_bounds__(256) void k_ff_mfma(float* __restrict__ xT,
                                                 const float* __restrict__ mean,
                                                 const float* __restrict__ rstd,
                                                 const float* __restrict__ g,
                                                 const float* __restrict__ be,
                                                 const unsigned short* __restrict__ w1pk,
                                                 const float* __restrict__ b1,
                                                 const unsigned short* __restrict__ w2pk,
                                                 const float* __restrict__ b2) {
  __shared__ unsigned short xa[32][136];   // A tile, padded
  __shared__ unsigned short hb[32][520];   // hidden, padded
  int tid = threadIdx.x, lane = tid & 63, w = tid >> 6;
  int row0 = blockIdx.x * 32;

  for (int e = tid; e < 32 * 64; e += 256) {      // 2 cols per elem
    int r = e >> 6, cp = e & 63;
    int row = row0 + r;
    float m = mean[row], rs = rstd[row];
    const float* xp = xT + (size_t)row * Cc + cp * 2;
    float v0 = (xp[0] - m) * rs * g[cp * 2] + be[cp * 2];
    float v1 = (xp[1] - m) * rs * g[cp * 2 + 1] + be[cp * 2 + 1];
    uint32_t u = (uint32_t)f2bf(v0) | ((uint32_t)f2bf(v1) << 16);
    *(uint32_t*)&xa[r][cp * 2] = u;
  }
  __syncthreads();

  // GEMM1: h = A @ w1  (wave w -> nt = w*8+nn)
  f32x4 acc[2][8];
#pragma unroll
  for (int m = 0; m < 2; ++m)
#pragma unroll
    for (int n = 0; n < 8; ++n) acc[m][n] = (f32x4){0.f, 0.f, 0.f, 0.f};
#pragma unroll
  for (int ks = 0; ks < 4; ++ks) {
    bf16x8 a0 = *(const bf16x8*)&xa[(lane & 15)][ks * 32 + (lane >> 4) * 8];
    bf16x8 a1 = *(const bf16x8*)&xa[16 + (lane & 15)][ks * 32 + (lane >> 4) * 8];
#pragma unroll
    for (int nn = 0; nn < 8; ++nn) {
      int ntg = w * 8 + nn;
      bf16x8 bf_ = *(const bf16x8*)&w1pk[((size_t)(ntg * 4 + ks) * 64 + lane) * 8];
      acc[0][nn] = __builtin_amdgcn_mfma_f32_16x16x32_bf16(a0, bf_, acc[0][nn], 0, 0, 0);
      acc[1][nn] = __builtin_amdgcn_mfma_f32_16x16x32_bf16(a1, bf_, acc[1][nn], 0, 0, 0);
    }
  }
#pragma unroll
  for (int m = 0; m < 2; ++m)
#pragma unroll
    for (int nn = 0; nn < 8; ++nn) {
      int col = (w * 8 + nn) * 16 + (lane & 15);
      float bb = b1[col];
#pragma unroll
      for (int i = 0; i < 4; ++i) {
        int r = m * 16 + (lane >> 4) * 4 + i;
        float h = acc[m][nn][i] + bb;
        hb[r][col] = f2bf(0.5f * h * (1.0f + erff(h * 0.70710678118654752f)));
      }
    }
  __syncthreads();

  // GEMM2: out = h @ w2 (wave w -> nt = w*2+nn), K=512
  f32x4 acc2[2][2];
#pragma unroll
  for (int m = 0; m < 2; ++m)
#pragma unroll
    for (int n = 0; n < 2; ++n) acc2[m][n] = (f32x4){0.f, 0.f, 0.f, 0.f};
#pragma unroll
  for (int ks = 0; ks < 16; ++ks) {
    bf16x8 a0 = *(const bf16x8*)&hb[(lane & 15)][ks * 32 + (lane >> 4) * 8];
    bf16x8 a1 = *(const bf16x8*)&hb[16 + (lane & 15)][ks * 32 + (lane >> 4) * 8];
#pragma unroll
    for (int nn = 0; nn < 2; ++nn) {
      int ntg = w * 2 + nn;
      bf16x8 bf_ = *(const bf16x8*)&w2pk[((size_t)(ntg * 16 + ks) * 64 + lane) * 8];
      acc2[0][nn] = __builtin_amdgcn_mfma_f32_16x16x32_bf16(a0, bf_, acc2[0][nn], 0, 0, 0);
      acc2[1][nn] = __builtin_amdgcn_mfma_f32_16x16x32_bf16(a1, bf_, acc2[1][nn], 0, 0, 0);
    }
  }
#pragma unroll
  for (int m = 0; m < 2; ++m)
#pragma unroll
    for (int nn = 0; nn < 2; ++nn) {
      int col = (w * 2 + nn) * 16 + (lane & 15);
      float bb = b2[col];
#pragma unroll
      for (int i = 0; i < 4; ++i) {
        int row = row0 + m * 16 + (lane >> 4) * 4 + i;
        xT[(size_t)row * Cc + col] += bb + acc2[m][nn][i];
      }
    }
}

// ---------- MFMA global-attn kv conv: kvg[16800][1024] bf16 ----------
__global__ __launch_bounds__(256) void k_gkv_mfma(const float* __restrict__ xT,
                                                  const float* __restrict__ mean,
                                                  const float* __restrict__ rstd,
                                                  const float* __restrict__ g,
                                                  const float* __restrict__ be,
                                                  const unsigned short* __restrict__ wkvpk,
                                                  unsigned short* __restrict__ kvg) {
  __shared__ unsigned short xa[32][136];
  int tid = threadIdx.x, lane = tid & 63, w = tid >> 6;
  int g0 = blockIdx.x * 32;
  int nh = blockIdx.y;                 // col half (0..1)
  f32x4 acc[2][8];
#pragma unroll
  for (int m = 0; m < 2; ++m)
#pragma unroll
    for (int n = 0; n < 8; ++n) acc[m][n] = (f32x4){0.f, 0.f, 0.f, 0.f};

  for (int kk = 0; kk < 7; ++kk) {
    __syncthreads();
    for (int e = tid; e < 32 * 64; e += 256) {
      int r = e >> 6, cp = e & 63;
      int grow = g0 + r;
      int b = grow / (TK * Vv), rem = grow % (TK * Vv), tk = rem / Vv, v = rem % Vv;
      int xrow = (b * Tt + tk * 7 + kk) * Vv + v;
      float m = mean[xrow], rs = rstd[xrow];
      const float* xp = xT + (size_t)xrow * Cc + cp * 2;
      float v0 = (xp[0] - m) * rs * g[cp * 2] + be[cp * 2];
      float v1 = (xp[1] - m) * rs * g[cp * 2 + 1] + be[cp * 2 + 1];
      *(uint32_t*)&xa[r][cp * 2] = (uint32_t)f2bf(v0) | ((uint32_t)f2bf(v1) << 16);
    }
    __syncthreads();
    const unsigned short* bp = wkvpk + kk * 131072;
#pragma unroll
    for (int ks = 0; ks < 4; ++ks) {
      bf16x8 a0 = *(const bf16x8*)&xa[(lane & 15)][ks * 32 + (lane >> 4) * 8];
      bf16x8 a1 = *(const bf16x8*)&xa[16 + (lane & 15)][ks * 32 + (lane >> 4) * 8];
#pragma unroll
      for (int nn = 0; nn < 8; ++nn) {
        int ntg = nh * 32 + w * 8 + nn;
        bf16x8 bf_ = *(const bf16x8*)&bp[((size_t)(ntg * 4 + ks) * 64 + lane) * 8];
        acc[0][nn] = __builtin_amdgcn_mfma_f32_16x16x32_bf16(a0, bf_, acc[0][nn], 0, 0, 0);
        acc[1][nn] = __builtin_amdgcn_mfma_f32_16x16x32_bf16(a1, bf_, acc[1][nn], 0, 0, 0);
      }
    }
  }
#pragma unroll
  for (int m = 0; m < 2; ++m)
#pragma unroll
    for (int nn = 0; nn < 8; ++nn) {
      int col = nh * 512 + (w * 8 + nn) * 16 + (lane & 15);
#pragma unroll
      for (int i = 0; i < 4; ++i) {
        int grow = g0 + m * 16 + (lane >> 4) * 4 + i;
        kvg[(size_t)grow * 1024 + col] = f2bf(acc[m][nn][i]);
      }
    }
}

// ---------- global attention core: per (b, v, 98-row chunk) ----------
__global__ __launch_bounds__(256) void k_gattn3(const float* __restrict__ xT,
                                                const float* __restrict__ mean,
                                                const float* __restrict__ rstd,
                                                const float* __restrict__ g,
                                                const float* __restrict__ be,
                                                const unsigned short* __restrict__ wqpk,
                                                const unsigned short* __restrict__ kvg,
                                                unsigned short* __restrict__ obuf) {
  __shared__ unsigned short xa[112][136];
  __shared__ unsigned short qh[112][66];
  __shared__ unsigned short kh[42][66];
  __shared__ unsigned short vh[42][66];
  int bid = blockIdx.x;
  int ch = bid % 3, v = (bid / 3) % Vv, b = bid / (3 * Vv);
  int t0 = ch * 98;
  int tid = threadIdx.x, lane = tid & 63, w = tid >> 6;

  for (int e = tid; e < 112 * 64; e += 256) {
    int r = e >> 6, cp = e & 63;
    uint32_t u = 0;
    if (r < 98) {
      int xrow = (b * Tt + t0 + r) * Vv + v;
      float m = mean[xrow], rs = rstd[xrow];
      const float* xp = xT + (size_t)xrow * Cc + cp * 2;
      float v0 = (xp[0] - m) * rs * g[cp * 2] + be[cp * 2];
      float v1 = (xp[1] - m) * rs * g[cp * 2 + 1] + be[cp * 2 + 1];
      u = (uint32_t)f2bf(v0) | ((uint32_t)f2bf(v1) << 16);
    }
    *(uint32_t*)&xa[r][cp * 2] = u;
  }

  for (int h = 0; h < NH; ++h) {
    __syncthreads();   // xa ready / prev-h consumers done
    // qh = A @ wq_h : 7mt x 4nt = 28 jobs, 7 per wave
#pragma unroll
    for (int jj = 0; jj < 7; ++jj) {
      int j = w * 7 + jj, mt = j >> 2, ntl = j & 3;
      f32x4 a4 = (f32x4){0.f, 0.f, 0.f, 0.f};
#pragma unroll
      for (int ks = 0; ks < 4; ++ks) {
        bf16x8 af = *(const bf16x8*)&xa[mt * 16 + (lane & 15)][ks * 32 + (lane >> 4) * 8];
        bf16x8 bf_ = *(const bf16x8*)&wqpk[((size_t)((h * 4 + ntl) * 4 + ks) * 64 + lane) * 8];
        a4 = __builtin_amdgcn_mfma_f32_16x16x32_bf16(af, bf_, a4, 0, 0, 0);
      }
#pragma unroll
      for (int i = 0; i < 4; ++i)
        qh[mt * 16 + (lane >> 4) * 4 + i][ntl * 16 + (lane & 15)] = f2bf(a4[i]);
    }
    // stage k_h, v_h (4B granule)
    for (int e = tid; e < 42 * 32; e += 256) {
      int j = e >> 5, dw = e & 31;
      const uint32_t* kr = (const uint32_t*)(kvg + ((size_t)(b * TK + j) * Vv + v) * 1024);
      *(uint32_t*)&kh[j][dw * 2] = kr[h * 32 + dw];
      *(uint32_t*)&vh[j][dw * 2] = kr[256 + h * 32 + dw];
    }
    __syncthreads();

    if (tid < 224) {
      int r = tid >> 1, half = tid & 1;
      float q[32];
#pragma unroll
      for (int c = 0; c < 16; ++c) {
        uint32_t u = *(const uint32_t*)&qh[r][half * 32 + c * 2];
        q[2 * c] = bflo(u); q[2 * c + 1] = bfhi(u);
      }
      float s[42];
      float mx = -1e30f;
#pragma unroll 2
      for (int j = 0; j < TK; ++j) {
        float acc = 0.f;
#pragma unroll
        for (int c = 0; c < 16; ++c) {
          uint32_t u = *(const uint32_t*)&kh[j][half * 32 + c * 2];
          acc += q[2 * c] * bflo(u) + q[2 * c + 1] * bfhi(u);
        }
        acc += __shfl_xor(acc, 1);
        s[j] = acc * SCALE;
        mx = fmaxf(mx, s[j]);
      }
      float sum = 0.f;
#pragma unroll
      for (int j = 0; j < TK; ++j) { s[j] = expf(s[j] - mx); sum += s[j]; }
      float inv = 1.0f / sum;
      float o[32];
#pragma unroll
      for (int c = 0; c < 32; ++c) o[c] = 0.f;
#pragma unroll 2
      for (int j = 0; j < TK; ++j) {
        float wgt = s[j] * inv;
#pragma unroll
        for (int c = 0; c < 16; ++c) {
          uint32_t u = *(const uint32_t*)&vh[j][half * 32 + c * 2];
          o[2 * c] += wgt * bflo(u);
          o[2 * c + 1] += wgt * bfhi(u);
        }
      }
      if (r < 98) {
        uint32_t* orow = (uint32_t*)(obuf + ((size_t)(b * Tt + t0 + r) * Vv + v) * 512);
#pragma unroll
        for (int c = 0; c < 16; ++c)
          orow[h * 32 + half * 16 + c] = (uint32_t)f2bf(o[2 * c]) | ((uint32_t)f2bf(o[2 * c + 1]) << 16);
      }
    }
  }
}

// ---------- MFMA proj + residual: xT += A[NPOS x 512] @ wo + bo ----------
__global__ __launch_bounds__(256) void k_proj_mfma(float* __restrict__ xT,
                                                   const unsigned short* __restrict__ A,
                                                   const unsigned short* __restrict__ wpk,
                                                   const float* __restrict__ bo) {
  int tid = threadIdx.x, lane = tid & 63, w = tid >> 6;
  int row0 = blockIdx.x * 32;
  f32x4 acc[2][2];
#pragma unroll
  for (int m = 0; m < 2; ++m)
#pragma unroll
    for (int n = 0; n < 2; ++n) acc[m][n] = (f32x4){0.f, 0.f, 0.f, 0.f};
#pragma unroll 4
  for (int ks = 0; ks < 16; ++ks) {
    bf16x8 a0 = *(const bf16x8*)&A[(size_t)(row0 + (lane & 15)) * 512 + ks * 32 + (lane >> 4) * 8];
    bf16x8 a1 = *(const bf16x8*)&A[(size_t)(row0 + 16 + (lane & 15)) * 512 + ks * 32 + (lane >> 4) * 8];
#pragma unroll
    for (int nn = 0; nn < 2; ++nn) {
      int ntg = w * 2 + nn;
      bf16x8 bf_ = *(const bf16x8*)&wpk[((size_t)(ntg * 16 + ks) * 64 + lane) * 8];
      acc[0][nn] = __builtin_amdgcn_mfma_f32_16x16x32_bf16(a0, bf_, acc[0][nn], 0, 0, 0);
      acc[1][nn] = __builtin_amdgcn_mfma_f32_16x16x32_bf16(a1, bf_, acc[1][nn], 0, 0, 0);
    }
  }
#pragma unroll
  for (int m = 0; m < 2; ++m)
#pragma unroll
    for (int nn = 0; nn < 2; ++nn) {
      int col = (w * 2 + nn) * 16 + (lane & 15);
      float bb = bo[col];
#pragma unroll
      for (int i = 0; i < 4; ++i) {
        int row = row0 + m * 16 + (lane >> 4) * 4 + i;
        xT[(size_t)row * Cc + col] += bb + acc[m][nn][i];
      }
    }
}

}  // namespace

extern "C" void kernel_launch(void* const* d_in, const int* in_sizes, int n_in,
                              void* d_out, int out_size, void* d_ws, size_t ws_size,
                              hipStream_t stream) {
  const float* x      = (const float*)d_in[0];
  const float* ln1_g  = (const float*)d_in[1];
  const float* ln1_b  = (const float*)d_in[2];
  const float* la_wq  = (const float*)d_in[3];
  const float* la_wkv = (const float*)d_in[4];
  const float* la_wo  = (const float*)d_in[5];
  const float* la_bo  = (const float*)d_in[6];
  const float* ln2_g  = (const float*)d_in[7];
  const float* ln2_b  = (const float*)d_in[8];
  const float* ff1_w1 = (const float*)d_in[9];
  const float* ff1_b1 = (const float*)d_in[10];
  const float* ff1_w2 = (const float*)d_in[11];
  const float* ff1_b2 = (const float*)d_in[12];
  const float* ln3_g  = (const float*)d_in[13];
  const float* ln3_b  = (const float*)d_in[14];
  const float* ga_wq  = (const float*)d_in[15];
  const float* ga_wkv = (const float*)d_in[16];
  const float* ga_wo  = (const float*)d_in[17];
  const float* ga_bo  = (const float*)d_in[18];
  const float* ln4_g  = (const float*)d_in[19];
  const float* ln4_b  = (const float*)d_in[20];
  const float* ff2_w1 = (const float*)d_in[21];
  const float* ff2_b1 = (const float*)d_in[22];
  const float* ff2_w2 = (const float*)d_in[23];
  const float* ff2_b2 = (const float*)d_in[24];

  float* xT   = (float*)d_ws;                          // NPOS*128 f32
  float* mean = xT + (size_t)NPOS * Cc;                // NPOS
  float* rstd = mean + NPOS;                           // NPOS
  unsigned short* obuf = (unsigned short*)(rstd + NPOS);      // NPOS*512 bf16
  unsigned short* kvg  = obuf + (size_t)NPOS * 512;           // 16800*1024 bf16
  unsigned short* wpk  = kvg + (size_t)NKV * 1024;            // packed weights

  // ---- pack weights (every launch; reads pristine d_in) ----
  hipLaunchKernelGGL(k_pack, dim3(32 * 4, 1, 2), dim3(64), 0, stream,
                     ff1_w1, wpk + OFF_FF1W1, 4, 512, (size_t)65536, LPK, 0, 0);
  hipLaunchKernelGGL(k_pack, dim3(8 * 16, 1, 2), dim3(64), 0, stream,
                     ff1_w2, wpk + OFF_FF1W2, 16, 128, (size_t)65536, LPK, 0, 0);
  hipLaunchKernelGGL(k_pack, dim3(32 * 4, 1, 2), dim3(64), 0, stream,
                     ff2_w1, wpk + OFF_FF2W1, 4, 512, (size_t)65536, LPK, 0, 0);
  hipLaunchKernelGGL(k_pack, dim3(8 * 16, 1, 2), dim3(64), 0, stream,
                     ff2_w2, wpk + OFF_FF2W2, 16, 128, (size_t)65536, LPK, 0, 0);
  hipLaunchKernelGGL(k_pack, dim3(32 * 4, 1, 2), dim3(64), 0, stream,
                     ga_wq, wpk + OFF_GAWQ, 4, 512, (size_t)65536, LPK, 0, 0);
  hipLaunchKernelGGL(k_pack, dim3(8 * 16, 1, 2), dim3(64), 0, stream,
                     ga_wo, wpk + OFF_GAWO, 16, 128, (size_t)65536, LPK, 0, 0);
  hipLaunchKernelGGL(k_pack, dim3(64 * 4, 7, 2), dim3(64), 0, stream,
                     ga_wkv, wpk + OFF_GAWKV, 4, 7168, (size_t)917504, LPK, 1024, 131072);

  dim3 blk2(32, 8);
  hipLaunchKernelGGL(k_transpose, dim3((TV + 31) / 32, (Cc + 31) / 32, Bb), blk2, 0, stream,
                     x, xT, Cc, TV);

  for (int i = 0; i < 2; ++i) {
    const unsigned short* lw = wpk + (size_t)i * LPK;

    hipLaunchKernelGGL(k_stats, dim3(NPOS / 4), dim3(256), 0, stream, xT, mean, rstd);
    hipLaunchKernelGGL(k_local, dim3(Bb * NT * Vv), dim3(256), 0, stream,
                       xT, mean, rstd, ln1_g + i * Cc, ln1_b + i * Cc,
                       la_wq + (size_t)i * Cc * INNER, la_wkv + (size_t)i * Cc * 2 * INNER,
                       la_wo + (size_t)i * INNER * Cc, la_bo + i * Cc);

    hipLaunchKernelGGL(k_stats, dim3(NPOS / 4), dim3(256), 0, stream, xT, mean, rstd);
    hipLaunchKernelGGL(k_ff_mfma, dim3(NPOS / 32), dim3(256), 0, stream,
                       xT, mean, rstd, ln2_g + i * Cc, ln2_b + i * Cc,
                       lw + OFF_FF1W1, ff1_b1 + i * HID, lw + OFF_FF1W2, ff1_b2 + i * Cc);

    hipLaunchKernelGGL(k_stats, dim3(NPOS / 4), dim3(256), 0, stream, xT, mean, rstd);
    hipLaunchKernelGGL(k_gkv_mfma, dim3(NKV / 32, 2), dim3(256), 0, stream,
                       xT, mean, rstd, ln3_g + i * Cc, ln3_b + i * Cc,
                       lw + OFF_GAWKV, kvg);
    hipLaunchKernelGGL(k_gattn3, dim3(Bb * Vv * 3), dim3(256), 0, stream,
                       xT, mean, rstd, ln3_g + i * Cc, ln3_b + i * Cc,
                       lw + OFF_GAWQ, kvg, obuf);
    hipLaunchKernelGGL(k_proj_mfma, dim3(NPOS / 32), dim3(256), 0, stream,
                       xT, obuf, lw + OFF_GAWO, ga_bo + i * Cc);

    hipLaunchKernelGGL(k_stats, dim3(NPOS / 4), dim3(256), 0, stream, xT, mean, rstd);
    hipLaunchKernelGGL(k_ff_mfma, dim3(NPOS / 32), dim3(256), 0, stream,
                       xT, mean, rstd, ln4_g + i * Cc, ln4_b + i * Cc,
                       lw + OFF_FF2W1, ff2_b1 + i * HID, lw + OFF_FF2W2, ff2_b2 + i * Cc);
  }

  hipLaunchKernelGGL(k_transpose, dim3((Cc + 31) / 32, (TV + 31) / 32, Bb), blk2, 0, stream,
                     xT, (float*)d_out, TV, Cc);
}

// Round 5
// 3470.064 us; speedup vs baseline: 4.9742x; 1.6460x over previous
//
#include <hip/hip_runtime.h>
#include <hip/hip_bf16.h>
#include <math.h>

namespace {

constexpr int Bb   = 16;
constexpr int Cc   = 128;
constexpr int Tt   = 294;
constexpr int Vv   = 25;
constexpr int TV   = Tt * Vv;        // 7350
constexpr int NPOS = Bb * TV;        // 117600
constexpr int INNER = 512;
constexpr int HID   = 512;
constexpr int NH    = 8;
constexpr int DH    = 64;
constexpr int Pp    = 7;
constexpr int Kk    = 7;
constexpr int NT    = 42;
constexpr int TK    = 42;            // T / K
constexpr int NKV   = Bb * TK * Vv;  // 16800 kv rows
constexpr float EPS   = 1e-5f;
constexpr float SCALE = 0.125f;

typedef __attribute__((ext_vector_type(8))) short bf16x8;
typedef __attribute__((ext_vector_type(4))) float f32x4;

__device__ inline float bflo(uint32_t u) { union { float f; uint32_t i; } x; x.i = u << 16; return x.f; }
__device__ inline float bfhi(uint32_t u) { union { float f; uint32_t i; } x; x.i = u & 0xffff0000u; return x.f; }
__device__ inline unsigned short f2bf(float f) {
  union { float f; uint32_t i; } x; x.f = f;
  uint32_t r = x.i + 0x7fffu + ((x.i >> 16) & 1u);
  return (unsigned short)(r >> 16);
}

// packed-weight offsets (elements), per-layer stride
constexpr int OFF_FF1W1 = 0;
constexpr int OFF_FF1W2 = 65536;
constexpr int OFF_FF2W1 = 131072;
constexpr int OFF_FF2W2 = 196608;
constexpr int OFF_GAWQ  = 262144;
constexpr int OFF_GAWO  = 327680;
constexpr int OFF_GAWKV = 393216;        // 7 * 131072
constexpr int OFF_LAWQ  = 1310720;
constexpr int OFF_LAWKV = 1376256;
constexpr int OFF_LAWO  = 1507328;
constexpr size_t LPK = 1572864;          // per-layer packed elements

// ---------- pack fp32 B[K x N] -> bf16 MFMA fragment layout ----------
// dst[((nt*nks+ks)*64 + lane)*8 + j] = B[ks*32 + (lane>>4)*8 + j][nt*16 + (lane&15)]
__global__ __launch_bounds__(64) void k_pack(const float* __restrict__ src,
                                             unsigned short* __restrict__ dst,
                                             int nks, int rowStride,
                                             size_t srcLayerStride, size_t dstLayerStride,
                                             int kkSrcOff, int kkDstOff) {
  int bid = blockIdx.x;
  int nt = bid / nks, ks = bid % nks;
  int l = threadIdx.x;
  const float* s = src + (size_t)blockIdx.z * srcLayerStride + (size_t)blockIdx.y * kkSrcOff;
  unsigned short* d = dst + (size_t)blockIdx.z * dstLayerStride + (size_t)blockIdx.y * kkDstOff
                      + ((size_t)bid * 64 + l) * 8;
  int rowb = ks * 32 + (l >> 4) * 8, col = nt * 16 + (l & 15);
  unsigned short tmp[8];
#pragma unroll
  for (int j = 0; j < 8; ++j) tmp[j] = f2bf(s[(size_t)(rowb + j) * rowStride + col]);
#pragma unroll
  for (int j = 0; j < 8; ++j) d[j] = tmp[j];
}

// ---------- batched transpose ----------
__global__ __launch_bounds__(256) void k_transpose(const float* __restrict__ src,
                                                   float* __restrict__ dst,
                                                   int M, int N) {
  __shared__ float tile[32][33];
  size_t off = (size_t)blockIdx.z * (size_t)M * (size_t)N;
  src += off; dst += off;
  int bx = blockIdx.x * 32, by = blockIdx.y * 32;
  int tx = threadIdx.x, ty = threadIdx.y;
#pragma unroll
  for (int r = 0; r < 4; ++r) {
    int row = by + ty + r * 8, col = bx + tx;
    if (row < M && col < N) tile[ty + r * 8][tx] = src[(size_t)row * N + col];
  }
  __syncthreads();
#pragma unroll
  for (int r = 0; r < 4; ++r) {
    int row = bx + ty + r * 8, col = by + tx;
    if (row < N && col < M) dst[(size_t)row * M + col] = tile[tx][ty + r * 8];
  }
}

// ---------- per-position LN stats ----------
__global__ __launch_bounds__(256) void k_stats(const float* __restrict__ xT,
                                               float* __restrict__ mean,
                                               float* __restrict__ rstd) {
  int row  = blockIdx.x * 4 + (threadIdx.x >> 6);
  int lane = threadIdx.x & 63;
  const float* p = xT + (size_t)row * Cc;
  float a = p[lane], b = p[lane + 64];
  float s = a + b, ss = a * a + b * b;
#pragma unroll
  for (int off = 32; off; off >>= 1) {
    s  += __shfl_xor(s, off);
    ss += __shfl_xor(ss, off);
  }
  if (lane == 0) {
    float m = s * (1.0f / Cc);
    mean[row] = m;
    rstd[row] = rsqrtf(ss * (1.0f / Cc) - m * m + EPS);
  }
}

// ---------- MFMA fused local attention: per (b, v, 49-row chunk = 7 patches) ----------
__global__ __launch_bounds__(256) void k_local_mfma(float* __restrict__ xT,
                                                    const float* __restrict__ mean,
                                                    const float* __restrict__ rstd,
                                                    const float* __restrict__ g,
                                                    const float* __restrict__ be,
                                                    const unsigned short* __restrict__ wqpk,
                                                    const unsigned short* __restrict__ wkvpk,
                                                    const unsigned short* __restrict__ wopk,
                                                    const float* __restrict__ bo) {
  constexpr int RR = 49;
  constexpr int QS = 72;   // shorts; 144 B stride keeps b128 reads 16B-aligned
  __shared__ unsigned short xa[64][136];
  __shared__ unsigned short qh[64][QS];
  __shared__ unsigned short kh[64][QS];
  __shared__ unsigned short vh[64][QS];
  __shared__ unsigned short oh[64][QS];
  int bid = blockIdx.x;
  int ch = bid % 6, v = (bid / 6) % Vv, b = bid / (6 * Vv);
  int t0 = ch * RR;
  int tid = threadIdx.x, lane = tid & 63, w = tid >> 6;

  // LN into xa (rows >= RR zero)
  for (int e = tid; e < 64 * 64; e += 256) {
    int r = e >> 6, cp = e & 63;
    uint32_t u = 0;
    if (r < RR) {
      int xrow = (b * Tt + t0 + r) * Vv + v;
      float m = mean[xrow], rs = rstd[xrow];
      const float* xp = xT + (size_t)xrow * Cc + cp * 2;
      float v0 = (xp[0] - m) * rs * g[cp * 2] + be[cp * 2];
      float v1 = (xp[1] - m) * rs * g[cp * 2 + 1] + be[cp * 2 + 1];
      u = (uint32_t)f2bf(v0) | ((uint32_t)f2bf(v1) << 16);
    }
    *(uint32_t*)&xa[r][cp * 2] = u;
  }
  // zero oh rows >= RR (attention never writes them; proj reads them)
  for (int e = tid; e < (64 - RR) * (QS / 2); e += 256) {
    int r = RR + e / (QS / 2), wd = e % (QS / 2);
    *(uint32_t*)&oh[r][wd * 2] = 0;
  }

  f32x4 acc2[8];
#pragma unroll
  for (int n = 0; n < 8; ++n) acc2[n] = (f32x4){0.f, 0.f, 0.f, 0.f};

  for (int h = 0; h < NH; ++h) {
    __syncthreads();   // xa/oh ready; prev head's attn reads of qh/kh/vh done
    // qkv projection for head h: 48 jobs (3 mats x 4 mt x 4 ntl), 12 per wave
#pragma unroll
    for (int jj = 0; jj < 12; ++jj) {
      int j = w * 12 + jj;
      int mat = j >> 4, mt = (j >> 2) & 3, ntl = j & 3;
      const unsigned short* bp = (mat == 0) ? wqpk : wkvpk;
      int ntg = (mat == 2 ? 32 : 0) + h * 4 + ntl;
      f32x4 a4 = (f32x4){0.f, 0.f, 0.f, 0.f};
#pragma unroll
      for (int ks = 0; ks < 4; ++ks) {
        bf16x8 af = *(const bf16x8*)&xa[mt * 16 + (lane & 15)][ks * 32 + (lane >> 4) * 8];
        bf16x8 bf_ = *(const bf16x8*)&bp[((size_t)(ntg * 4 + ks) * 64 + lane) * 8];
        a4 = __builtin_amdgcn_mfma_f32_16x16x32_bf16(af, bf_, a4, 0, 0, 0);
      }
      unsigned short* dstp = (mat == 0) ? &qh[0][0] : (mat == 1 ? &kh[0][0] : &vh[0][0]);
#pragma unroll
      for (int i = 0; i < 4; ++i)
        dstp[(mt * 16 + (lane >> 4) * 4 + i) * QS + ntl * 16 + (lane & 15)] = f2bf(a4[i]);
    }
    __syncthreads();
    // attention: 2 threads per row (d-halves), rows 0..RR-1
    if (tid < 2 * RR) {
      int r = tid >> 1, half = tid & 1;
      int pbase = (r / 7) * 7;
      float q[32];
#pragma unroll
      for (int c = 0; c < 16; ++c) {
        uint32_t u = *(const uint32_t*)&qh[r][half * 32 + c * 2];
        q[2 * c] = bflo(u); q[2 * c + 1] = bfhi(u);
      }
      float s[Pp];
      float mx = -1e30f;
#pragma unroll
      for (int j = 0; j < Pp; ++j) {
        float acc = 0.f;
#pragma unroll
        for (int c = 0; c < 16; ++c) {
          uint32_t u = *(const uint32_t*)&kh[pbase + j][half * 32 + c * 2];
          acc += q[2 * c] * bflo(u) + q[2 * c + 1] * bfhi(u);
        }
        acc += __shfl_xor(acc, 1);
        s[j] = acc * SCALE;
        mx = fmaxf(mx, s[j]);
      }
      float sum = 0.f;
#pragma unroll
      for (int j = 0; j < Pp; ++j) { s[j] = expf(s[j] - mx); sum += s[j]; }
      float inv = 1.0f / sum;
      float o[32];
#pragma unroll
      for (int c = 0; c < 32; ++c) o[c] = 0.f;
#pragma unroll
      for (int j = 0; j < Pp; ++j) {
        float wgt = s[j] * inv;
#pragma unroll
        for (int c = 0; c < 16; ++c) {
          uint32_t u = *(const uint32_t*)&vh[pbase + j][half * 32 + c * 2];
          o[2 * c] += wgt * bflo(u);
          o[2 * c + 1] += wgt * bfhi(u);
        }
      }
#pragma unroll
      for (int c = 0; c < 16; ++c)
        *(uint32_t*)&oh[r][half * 32 + c * 2] =
            (uint32_t)f2bf(o[2 * c]) | ((uint32_t)f2bf(o[2 * c + 1]) << 16);
    }
    __syncthreads();
    // proj accumulate: wave w owns m-tile w; nt 0..7; K rows h*64.. -> ks = 2h+ksl
#pragma unroll
    for (int ksl = 0; ksl < 2; ++ksl) {
      bf16x8 af = *(const bf16x8*)&oh[w * 16 + (lane & 15)][ksl * 32 + (lane >> 4) * 8];
#pragma unroll
      for (int nn = 0; nn < 8; ++nn) {
        bf16x8 bf_ = *(const bf16x8*)&wopk[((size_t)(nn * 16 + h * 2 + ksl) * 64 + lane) * 8];
        acc2[nn] = __builtin_amdgcn_mfma_f32_16x16x32_bf16(af, bf_, acc2[nn], 0, 0, 0);
      }
    }
  }
  // epilogue: bias + residual
#pragma unroll
  for (int nn = 0; nn < 8; ++nn) {
    int col = nn * 16 + (lane & 15);
    float bb = bo[col];
#pragma unroll
    for (int i = 0; i < 4; ++i) {
      int r = w * 16 + (lane >> 4) * 4 + i;
      if (r < RR) {
        int row = (b * Tt + t0 + r) * Vv + v;
        xT[(size_t)row * Cc + col] += bb + acc2[nn][i];
      }
    }
  }
}

// ---------- MFMA fused feed-forward: 32 rows/block ----------
__global__ __launch_bounds__(256) void k_ff_mfma(float* __restrict__ xT,
                                                 const float* __restrict__ mean,
                                                 const float* __restrict__ rstd,
                                                 const float* __restrict__ g,
                                                 const float* __restrict__ be,
                                                 const unsigned short* __restrict__ w1pk,
                                                 const float* __restrict__ b1,
                                                 const unsigned short* __restrict__ w2pk,
                                                 const float* __restrict__ b2) {
  __shared__ unsigned short xa[32][136];   // A tile, padded
  __shared__ unsigned short hb[32][520];   // hidden, padded
  int tid = threadIdx.x, lane = tid & 63, w = tid >> 6;
  int row0 = blockIdx.x * 32;

  for (int e = tid; e < 32 * 64; e += 256) {
    int r = e >> 6, cp = e & 63;
    int row = row0 + r;
    float m = mean[row], rs = rstd[row];
    const float* xp = xT + (size_t)row * Cc + cp * 2;
    float v0 = (xp[0] - m) * rs * g[cp * 2] + be[cp * 2];
    float v1 = (xp[1] - m) * rs * g[cp * 2 + 1] + be[cp * 2 + 1];
    uint32_t u = (uint32_t)f2bf(v0) | ((uint32_t)f2bf(v1) << 16);
    *(uint32_t*)&xa[r][cp * 2] = u;
  }
  __syncthreads();

  f32x4 acc[2][8];
#pragma unroll
  for (int m = 0; m < 2; ++m)
#pragma unroll
    for (int n = 0; n < 8; ++n) acc[m][n] = (f32x4){0.f, 0.f, 0.f, 0.f};
#pragma unroll
  for (int ks = 0; ks < 4; ++ks) {
    bf16x8 a0 = *(const bf16x8*)&xa[(lane & 15)][ks * 32 + (lane >> 4) * 8];
    bf16x8 a1 = *(const bf16x8*)&xa[16 + (lane & 15)][ks * 32 + (lane >> 4) * 8];
#pragma unroll
    for (int nn = 0; nn < 8; ++nn) {
      int ntg = w * 8 + nn;
      bf16x8 bf_ = *(const bf16x8*)&w1pk[((size_t)(ntg * 4 + ks) * 64 + lane) * 8];
      acc[0][nn] = __builtin_amdgcn_mfma_f32_16x16x32_bf16(a0, bf_, acc[0][nn], 0, 0, 0);
      acc[1][nn] = __builtin_amdgcn_mfma_f32_16x16x32_bf16(a1, bf_, acc[1][nn], 0, 0, 0);
    }
  }
#pragma unroll
  for (int m = 0; m < 2; ++m)
#pragma unroll
    for (int nn = 0; nn < 8; ++nn) {
      int col = (w * 8 + nn) * 16 + (lane & 15);
      float bb = b1[col];
#pragma unroll
      for (int i = 0; i < 4; ++i) {
        int r = m * 16 + (lane >> 4) * 4 + i;
        float h = acc[m][nn][i] + bb;
        hb[r][col] = f2bf(0.5f * h * (1.0f + erff(h * 0.70710678118654752f)));
      }
    }
  __syncthreads();

  f32x4 acc2[2][2];
#pragma unroll
  for (int m = 0; m < 2; ++m)
#pragma unroll
    for (int n = 0; n < 2; ++n) acc2[m][n] = (f32x4){0.f, 0.f, 0.f, 0.f};
#pragma unroll
  for (int ks = 0; ks < 16; ++ks) {
    bf16x8 a0 = *(const bf16x8*)&hb[(lane & 15)][ks * 32 + (lane >> 4) * 8];
    bf16x8 a1 = *(const bf16x8*)&hb[16 + (lane & 15)][ks * 32 + (lane >> 4) * 8];
#pragma unroll
    for (int nn = 0; nn < 2; ++nn) {
      int ntg = w * 2 + nn;
      bf16x8 bf_ = *(const bf16x8*)&w2pk[((size_t)(ntg * 16 + ks) * 64 + lane) * 8];
      acc2[0][nn] = __builtin_amdgcn_mfma_f32_16x16x32_bf16(a0, bf_, acc2[0][nn], 0, 0, 0);
      acc2[1][nn] = __builtin_amdgcn_mfma_f32_16x16x32_bf16(a1, bf_, acc2[1][nn], 0, 0, 0);
    }
  }
#pragma unroll
  for (int m = 0; m < 2; ++m)
#pragma unroll
    for (int nn = 0; nn < 2; ++nn) {
      int col = (w * 2 + nn) * 16 + (lane & 15);
      float bb = b2[col];
#pragma unroll
      for (int i = 0; i < 4; ++i) {
        int row = row0 + m * 16 + (lane >> 4) * 4 + i;
        xT[(size_t)row * Cc + col] += bb + acc2[m][nn][i];
      }
    }
}

// ---------- MFMA global-attn kv conv: kvg[16800][1024] bf16 ----------
__global__ __launch_bounds__(256) void k_gkv_mfma(const float* __restrict__ xT,
                                                  const float* __restrict__ mean,
                                                  const float* __restrict__ rstd,
                                                  const float* __restrict__ g,
                                                  const float* __restrict__ be,
                                                  const unsigned short* __restrict__ wkvpk,
                                                  unsigned short* __restrict__ kvg) {
  __shared__ unsigned short xa[32][136];
  int tid = threadIdx.x, lane = tid & 63, w = tid >> 6;
  int g0 = blockIdx.x * 32;
  int nh = blockIdx.y;
  f32x4 acc[2][8];
#pragma unroll
  for (int m = 0; m < 2; ++m)
#pragma unroll
    for (int n = 0; n < 8; ++n) acc[m][n] = (f32x4){0.f, 0.f, 0.f, 0.f};

  for (int kk = 0; kk < 7; ++kk) {
    __syncthreads();
    for (int e = tid; e < 32 * 64; e += 256) {
      int r = e >> 6, cp = e & 63;
      int grow = g0 + r;
      int b = grow / (TK * Vv), rem = grow % (TK * Vv), tk = rem / Vv, v = rem % Vv;
      int xrow = (b * Tt + tk * 7 + kk) * Vv + v;
      float m = mean[xrow], rs = rstd[xrow];
      const float* xp = xT + (size_t)xrow * Cc + cp * 2;
      float v0 = (xp[0] - m) * rs * g[cp * 2] + be[cp * 2];
      float v1 = (xp[1] - m) * rs * g[cp * 2 + 1] + be[cp * 2 + 1];
      *(uint32_t*)&xa[r][cp * 2] = (uint32_t)f2bf(v0) | ((uint32_t)f2bf(v1) << 16);
    }
    __syncthreads();
    const unsigned short* bp = wkvpk + kk * 131072;
#pragma unroll
    for (int ks = 0; ks < 4; ++ks) {
      bf16x8 a0 = *(const bf16x8*)&xa[(lane & 15)][ks * 32 + (lane >> 4) * 8];
      bf16x8 a1 = *(const bf16x8*)&xa[16 + (lane & 15)][ks * 32 + (lane >> 4) * 8];
#pragma unroll
      for (int nn = 0; nn < 8; ++nn) {
        int ntg = nh * 32 + w * 8 + nn;
        bf16x8 bf_ = *(const bf16x8*)&bp[((size_t)(ntg * 4 + ks) * 64 + lane) * 8];
        acc[0][nn] = __builtin_amdgcn_mfma_f32_16x16x32_bf16(a0, bf_, acc[0][nn], 0, 0, 0);
        acc[1][nn] = __builtin_amdgcn_mfma_f32_16x16x32_bf16(a1, bf_, acc[1][nn], 0, 0, 0);
      }
    }
  }
#pragma unroll
  for (int m = 0; m < 2; ++m)
#pragma unroll
    for (int nn = 0; nn < 8; ++nn) {
      int col = nh * 512 + (w * 8 + nn) * 16 + (lane & 15);
#pragma unroll
      for (int i = 0; i < 4; ++i) {
        int grow = g0 + m * 16 + (lane >> 4) * 4 + i;
        kvg[(size_t)grow * 1024 + col] = f2bf(acc[m][nn][i]);
      }
    }
}

// ---------- global attention core: per (b, v, 98-row chunk) ----------
__global__ __launch_bounds__(256) void k_gattn3(const float* __restrict__ xT,
                                                const float* __restrict__ mean,
                                                const float* __restrict__ rstd,
                                                const float* __restrict__ g,
                                                const float* __restrict__ be,
                                                const unsigned short* __restrict__ wqpk,
                                                const unsigned short* __restrict__ kvg,
                                                unsigned short* __restrict__ obuf) {
  __shared__ unsigned short xa[112][136];
  __shared__ unsigned short qh[112][66];
  __shared__ unsigned short kh[42][66];
  __shared__ unsigned short vh[42][66];
  int bid = blockIdx.x;
  int ch = bid % 3, v = (bid / 3) % Vv, b = bid / (3 * Vv);
  int t0 = ch * 98;
  int tid = threadIdx.x, lane = tid & 63, w = tid >> 6;

  for (int e = tid; e < 112 * 64; e += 256) {
    int r = e >> 6, cp = e & 63;
    uint32_t u = 0;
    if (r < 98) {
      int xrow = (b * Tt + t0 + r) * Vv + v;
      float m = mean[xrow], rs = rstd[xrow];
      const float* xp = xT + (size_t)xrow * Cc + cp * 2;
      float v0 = (xp[0] - m) * rs * g[cp * 2] + be[cp * 2];
      float v1 = (xp[1] - m) * rs * g[cp * 2 + 1] + be[cp * 2 + 1];
      u = (uint32_t)f2bf(v0) | ((uint32_t)f2bf(v1) << 16);
    }
    *(uint32_t*)&xa[r][cp * 2] = u;
  }

  for (int h = 0; h < NH; ++h) {
    __syncthreads();
#pragma unroll
    for (int jj = 0; jj < 7; ++jj) {
      int j = w * 7 + jj, mt = j >> 2, ntl = j & 3;
      f32x4 a4 = (f32x4){0.f, 0.f, 0.f, 0.f};
#pragma unroll
      for (int ks = 0; ks < 4; ++ks) {
        bf16x8 af = *(const bf16x8*)&xa[mt * 16 + (lane & 15)][ks * 32 + (lane >> 4) * 8];
        bf16x8 bf_ = *(const bf16x8*)&wqpk[((size_t)((h * 4 + ntl) * 4 + ks) * 64 + lane) * 8];
        a4 = __builtin_amdgcn_mfma_f32_16x16x32_bf16(af, bf_, a4, 0, 0, 0);
      }
#pragma unroll
      for (int i = 0; i < 4; ++i)
        qh[mt * 16 + (lane >> 4) * 4 + i][ntl * 16 + (lane & 15)] = f2bf(a4[i]);
    }
    for (int e = tid; e < 42 * 32; e += 256) {
      int j = e >> 5, dw = e & 31;
      const uint32_t* kr = (const uint32_t*)(kvg + ((size_t)(b * TK + j) * Vv + v) * 1024);
      *(uint32_t*)&kh[j][dw * 2] = kr[h * 32 + dw];
      *(uint32_t*)&vh[j][dw * 2] = kr[256 + h * 32 + dw];
    }
    __syncthreads();

    if (tid < 224) {
      int r = tid >> 1, half = tid & 1;
      float q[32];
#pragma unroll
      for (int c = 0; c < 16; ++c) {
        uint32_t u = *(const uint32_t*)&qh[r][half * 32 + c * 2];
        q[2 * c] = bflo(u); q[2 * c + 1] = bfhi(u);
      }
      float s[42];
      float mx = -1e30f;
#pragma unroll 2
      for (int j = 0; j < TK; ++j) {
        float acc = 0.f;
#pragma unroll
        for (int c = 0; c < 16; ++c) {
          uint32_t u = *(const uint32_t*)&kh[j][half * 32 + c * 2];
          acc += q[2 * c] * bflo(u) + q[2 * c + 1] * bfhi(u);
        }
        acc += __shfl_xor(acc, 1);
        s[j] = acc * SCALE;
        mx = fmaxf(mx, s[j]);
      }
      float sum = 0.f;
#pragma unroll
      for (int j = 0; j < TK; ++j) { s[j] = expf(s[j] - mx); sum += s[j]; }
      float inv = 1.0f / sum;
      float o[32];
#pragma unroll
      for (int c = 0; c < 32; ++c) o[c] = 0.f;
#pragma unroll 2
      for (int j = 0; j < TK; ++j) {
        float wgt = s[j] * inv;
#pragma unroll
        for (int c = 0; c < 16; ++c) {
          uint32_t u = *(const uint32_t*)&vh[j][half * 32 + c * 2];
          o[2 * c] += wgt * bflo(u);
          o[2 * c + 1] += wgt * bfhi(u);
        }
      }
      if (r < 98) {
        uint32_t* orow = (uint32_t*)(obuf + ((size_t)(b * Tt + t0 + r) * Vv + v) * 512);
#pragma unroll
        for (int c = 0; c < 16; ++c)
          orow[h * 32 + half * 16 + c] = (uint32_t)f2bf(o[2 * c]) | ((uint32_t)f2bf(o[2 * c + 1]) << 16);
      }
    }
  }
}

// ---------- MFMA proj + residual: xT += A[NPOS x 512] @ wo + bo ----------
__global__ __launch_bounds__(256) void k_proj_mfma(float* __restrict__ xT,
                                                   const unsigned short* __restrict__ A,
                                                   const unsigned short* __restrict__ wpk,
                                                   const float* __restrict__ bo) {
  int tid = threadIdx.x, lane = tid & 63, w = tid >> 6;
  int row0 = blockIdx.x * 32;
  f32x4 acc[2][2];
#pragma unroll
  for (int m = 0; m < 2; ++m)
#pragma unroll
    for (int n = 0; n < 2; ++n) acc[m][n] = (f32x4){0.f, 0.f, 0.f, 0.f};
#pragma unroll 4
  for (int ks = 0; ks < 16; ++ks) {
    bf16x8 a0 = *(const bf16x8*)&A[(size_t)(row0 + (lane & 15)) * 512 + ks * 32 + (lane >> 4) * 8];
    bf16x8 a1 = *(const bf16x8*)&A[(size_t)(row0 + 16 + (lane & 15)) * 512 + ks * 32 + (lane >> 4) * 8];
#pragma unroll
    for (int nn = 0; nn < 2; ++nn) {
      int ntg = w * 2 + nn;
      bf16x8 bf_ = *(const bf16x8*)&wpk[((size_t)(ntg * 16 + ks) * 64 + lane) * 8];
      acc[0][nn] = __builtin_amdgcn_mfma_f32_16x16x32_bf16(a0, bf_, acc[0][nn], 0, 0, 0);
      acc[1][nn] = __builtin_amdgcn_mfma_f32_16x16x32_bf16(a1, bf_, acc[1][nn], 0, 0, 0);
    }
  }
#pragma unroll
  for (int m = 0; m < 2; ++m)
#pragma unroll
    for (int nn = 0; nn < 2; ++nn) {
      int col = (w * 2 + nn) * 16 + (lane & 15);
      float bb = bo[col];
#pragma unroll
      for (int i = 0; i < 4; ++i) {
        int row = row0 + m * 16 + (lane >> 4) * 4 + i;
        xT[(size_t)row * Cc + col] += bb + acc[m][nn][i];
      }
    }
}

}  // namespace

extern "C" void kernel_launch(void* const* d_in, const int* in_sizes, int n_in,
                              void* d_out, int out_size, void* d_ws, size_t ws_size,
                              hipStream_t stream) {
  const float* x      = (const float*)d_in[0];
  const float* ln1_g  = (const float*)d_in[1];
  const float* ln1_b  = (const float*)d_in[2];
  const float* la_wq  = (const float*)d_in[3];
  const float* la_wkv = (const float*)d_in[4];
  const float* la_wo  = (const float*)d_in[5];
  const float* la_bo  = (const float*)d_in[6];
  const float* ln2_g  = (const float*)d_in[7];
  const float* ln2_b  = (const float*)d_in[8];
  const float* ff1_w1 = (const float*)d_in[9];
  const float* ff1_b1 = (const float*)d_in[10];
  const float* ff1_w2 = (const float*)d_in[11];
  const float* ff1_b2 = (const float*)d_in[12];
  const float* ln3_g  = (const float*)d_in[13];
  const float* ln3_b  = (const float*)d_in[14];
  const float* ga_wq  = (const float*)d_in[15];
  const float* ga_wkv = (const float*)d_in[16];
  const float* ga_wo  = (const float*)d_in[17];
  const float* ga_bo  = (const float*)d_in[18];
  const float* ln4_g  = (const float*)d_in[19];
  const float* ln4_b  = (const float*)d_in[20];
  const float* ff2_w1 = (const float*)d_in[21];
  const float* ff2_b1 = (const float*)d_in[22];
  const float* ff2_w2 = (const float*)d_in[23];
  const float* ff2_b2 = (const float*)d_in[24];

  float* xT   = (float*)d_ws;                          // NPOS*128 f32
  float* mean = xT + (size_t)NPOS * Cc;                // NPOS
  float* rstd = mean + NPOS;                           // NPOS
  unsigned short* obuf = (unsigned short*)(rstd + NPOS);      // NPOS*512 bf16
  unsigned short* kvg  = obuf + (size_t)NPOS * 512;           // 16800*1024 bf16
  unsigned short* wpk  = kvg + (size_t)NKV * 1024;            // packed weights

  // ---- pack weights ----
  hipLaunchKernelGGL(k_pack, dim3(32 * 4, 1, 2), dim3(64), 0, stream,
                     ff1_w1, wpk + OFF_FF1W1, 4, 512, (size_t)65536, LPK, 0, 0);
  hipLaunchKernelGGL(k_pack, dim3(8 * 16, 1, 2), dim3(64), 0, stream,
                     ff1_w2, wpk + OFF_FF1W2, 16, 128, (size_t)65536, LPK, 0, 0);
  hipLaunchKernelGGL(k_pack, dim3(32 * 4, 1, 2), dim3(64), 0, stream,
                     ff2_w1, wpk + OFF_FF2W1, 4, 512, (size_t)65536, LPK, 0, 0);
  hipLaunchKernelGGL(k_pack, dim3(8 * 16, 1, 2), dim3(64), 0, stream,
                     ff2_w2, wpk + OFF_FF2W2, 16, 128, (size_t)65536, LPK, 0, 0);
  hipLaunchKernelGGL(k_pack, dim3(32 * 4, 1, 2), dim3(64), 0, stream,
                     ga_wq, wpk + OFF_GAWQ, 4, 512, (size_t)65536, LPK, 0, 0);
  hipLaunchKernelGGL(k_pack, dim3(8 * 16, 1, 2), dim3(64), 0, stream,
                     ga_wo, wpk + OFF_GAWO, 16, 128, (size_t)65536, LPK, 0, 0);
  hipLaunchKernelGGL(k_pack, dim3(64 * 4, 7, 2), dim3(64), 0, stream,
                     ga_wkv, wpk + OFF_GAWKV, 4, 7168, (size_t)917504, LPK, 1024, 131072);
  hipLaunchKernelGGL(k_pack, dim3(32 * 4, 1, 2), dim3(64), 0, stream,
                     la_wq, wpk + OFF_LAWQ, 4, 512, (size_t)65536, LPK, 0, 0);
  hipLaunchKernelGGL(k_pack, dim3(64 * 4, 1, 2), dim3(64), 0, stream,
                     la_wkv, wpk + OFF_LAWKV, 4, 1024, (size_t)131072, LPK, 0, 0);
  hipLaunchKernelGGL(k_pack, dim3(8 * 16, 1, 2), dim3(64), 0, stream,
                     la_wo, wpk + OFF_LAWO, 16, 128, (size_t)65536, LPK, 0, 0);

  dim3 blk2(32, 8);
  hipLaunchKernelGGL(k_transpose, dim3((TV + 31) / 32, (Cc + 31) / 32, Bb), blk2, 0, stream,
                     x, xT, Cc, TV);

  for (int i = 0; i < 2; ++i) {
    const unsigned short* lw = wpk + (size_t)i * LPK;

    hipLaunchKernelGGL(k_stats, dim3(NPOS / 4), dim3(256), 0, stream, xT, mean, rstd);
    hipLaunchKernelGGL(k_local_mfma, dim3(Bb * Vv * 6), dim3(256), 0, stream,
                       xT, mean, rstd, ln1_g + i * Cc, ln1_b + i * Cc,
                       lw + OFF_LAWQ, lw + OFF_LAWKV, lw + OFF_LAWO, la_bo + i * Cc);

    hipLaunchKernelGGL(k_stats, dim3(NPOS / 4), dim3(256), 0, stream, xT, mean, rstd);
    hipLaunchKernelGGL(k_ff_mfma, dim3(NPOS / 32), dim3(256), 0, stream,
                       xT, mean, rstd, ln2_g + i * Cc, ln2_b + i * Cc,
                       lw + OFF_FF1W1, ff1_b1 + i * HID, lw + OFF_FF1W2, ff1_b2 + i * Cc);

    hipLaunchKernelGGL(k_stats, dim3(NPOS / 4), dim3(256), 0, stream, xT, mean, rstd);
    hipLaunchKernelGGL(k_gkv_mfma, dim3(NKV / 32, 2), dim3(256), 0, stream,
                       xT, mean, rstd, ln3_g + i * Cc, ln3_b + i * Cc,
                       lw + OFF_GAWKV, kvg);
    hipLaunchKernelGGL(k_gattn3, dim3(Bb * Vv * 3), dim3(256), 0, stream,
                       xT, mean, rstd, ln3_g + i * Cc, ln3_b + i * Cc,
                       lw + OFF_GAWQ, kvg, obuf);
    hipLaunchKernelGGL(k_proj_mfma, dim3(NPOS / 32), dim3(256), 0, stream,
                       xT, obuf, lw + OFF_GAWO, ga_bo + i * Cc);

    hipLaunchKernelGGL(k_stats, dim3(NPOS / 4), dim3(256), 0, stream, xT, mean, rstd);
    hipLaunchKernelGGL(k_ff_mfma, dim3(NPOS / 32), dim3(256), 0, stream,
                       xT, mean, rstd, ln4_g + i * Cc, ln4_b + i * Cc,
                       lw + OFF_FF2W1, ff2_b1 + i * HID, lw + OFF_FF2W2, ff2_b2 + i * Cc);
  }

  hipLaunchKernelGGL(k_transpose, dim3((Cc + 31) / 32, (TV + 31) / 32, Bb), blk2, 0, stream,
                     xT, (float*)d_out, TV, Cc);
}

// Round 6
// 2776.627 us; speedup vs baseline: 6.2165x; 1.2497x over previous
//
#include <hip/hip_runtime.h>
#include <hip/hip_bf16.h>
#include <math.h>

namespace {

constexpr int Bb   = 16;
constexpr int Cc   = 128;
constexpr int Tt   = 294;
constexpr int Vv   = 25;
constexpr int TV   = Tt * Vv;        // 7350
constexpr int NPOS = Bb * TV;        // 117600
constexpr int INNER = 512;
constexpr int HID   = 512;
constexpr int NH    = 8;
constexpr int DH    = 64;
constexpr int Pp    = 7;
constexpr int Kk    = 7;
constexpr int NT    = 42;
constexpr int TK    = 42;            // T / K
constexpr int NKV   = Bb * TK * Vv;  // 16800 kv rows
constexpr float EPS   = 1e-5f;
constexpr float SCALE = 0.125f;

typedef __attribute__((ext_vector_type(8))) short bf16x8;
typedef __attribute__((ext_vector_type(4))) float f32x4;

__device__ inline float bflo(uint32_t u) { union { float f; uint32_t i; } x; x.i = u << 16; return x.f; }
__device__ inline float bfhi(uint32_t u) { union { float f; uint32_t i; } x; x.i = u & 0xffff0000u; return x.f; }
__device__ inline unsigned short f2bf(float f) {
  union { float f; uint32_t i; } x; x.f = f;
  uint32_t r = x.i + 0x7fffu + ((x.i >> 16) & 1u);
  return (unsigned short)(r >> 16);
}

// packed-weight offsets (elements), per-layer stride
constexpr int OFF_FF1W1 = 0;
constexpr int OFF_FF1W2 = 65536;
constexpr int OFF_FF2W1 = 131072;
constexpr int OFF_FF2W2 = 196608;
constexpr int OFF_GAWQ  = 262144;
constexpr int OFF_GAWO  = 327680;
constexpr int OFF_GAWKV = 393216;        // 7 * 131072
constexpr int OFF_LAWQ  = 1310720;
constexpr int OFF_LAWKV = 1376256;
constexpr int OFF_LAWO  = 1507328;
constexpr size_t LPK = 1572864;          // per-layer packed elements

// ---------- pack fp32 B[K x N] -> bf16 MFMA fragment layout ----------
__global__ __launch_bounds__(64) void k_pack(const float* __restrict__ src,
                                             unsigned short* __restrict__ dst,
                                             int nks, int rowStride,
                                             size_t srcLayerStride, size_t dstLayerStride,
                                             int kkSrcOff, int kkDstOff) {
  int bid = blockIdx.x;
  int nt = bid / nks, ks = bid % nks;
  int l = threadIdx.x;
  const float* s = src + (size_t)blockIdx.z * srcLayerStride + (size_t)blockIdx.y * kkSrcOff;
  unsigned short* d = dst + (size_t)blockIdx.z * dstLayerStride + (size_t)blockIdx.y * kkDstOff
                      + ((size_t)bid * 64 + l) * 8;
  int rowb = ks * 32 + (l >> 4) * 8, col = nt * 16 + (l & 15);
  unsigned short tmp[8];
#pragma unroll
  for (int j = 0; j < 8; ++j) tmp[j] = f2bf(s[(size_t)(rowb + j) * rowStride + col]);
#pragma unroll
  for (int j = 0; j < 8; ++j) d[j] = tmp[j];
}

// ---------- batched transpose ----------
__global__ __launch_bounds__(256) void k_transpose(const float* __restrict__ src,
                                                   float* __restrict__ dst,
                                                   int M, int N) {
  __shared__ float tile[32][33];
  size_t off = (size_t)blockIdx.z * (size_t)M * (size_t)N;
  src += off; dst += off;
  int bx = blockIdx.x * 32, by = blockIdx.y * 32;
  int tx = threadIdx.x, ty = threadIdx.y;
#pragma unroll
  for (int r = 0; r < 4; ++r) {
    int row = by + ty + r * 8, col = bx + tx;
    if (row < M && col < N) tile[ty + r * 8][tx] = src[(size_t)row * N + col];
  }
  __syncthreads();
#pragma unroll
  for (int r = 0; r < 4; ++r) {
    int row = bx + ty + r * 8, col = by + tx;
    if (row < N && col < M) dst[(size_t)row * M + col] = tile[tx][ty + r * 8];
  }
}

// ---------- per-position LN stats ----------
__global__ __launch_bounds__(256) void k_stats(const float* __restrict__ xT,
                                               float* __restrict__ mean,
                                               float* __restrict__ rstd) {
  int row  = blockIdx.x * 4 + (threadIdx.x >> 6);
  int lane = threadIdx.x & 63;
  const float* p = xT + (size_t)row * Cc;
  float a = p[lane], b = p[lane + 64];
  float s = a + b, ss = a * a + b * b;
#pragma unroll
  for (int off = 32; off; off >>= 1) {
    s  += __shfl_xor(s, off);
    ss += __shfl_xor(ss, off);
  }
  if (lane == 0) {
    float m = s * (1.0f / Cc);
    mean[row] = m;
    rstd[row] = rsqrtf(ss * (1.0f / Cc) - m * m + EPS);
  }
}

// ---------- MFMA fused local attention: per (b, v, 49-row chunk = 7 patches) ----------
__global__ __launch_bounds__(256) void k_local_mfma(float* __restrict__ xT,
                                                    const float* __restrict__ mean,
                                                    const float* __restrict__ rstd,
                                                    const float* __restrict__ g,
                                                    const float* __restrict__ be,
                                                    const unsigned short* __restrict__ wqpk,
                                                    const unsigned short* __restrict__ wkvpk,
                                                    const unsigned short* __restrict__ wopk,
                                                    const float* __restrict__ bo) {
  constexpr int RR = 49;
  constexpr int QS = 72;
  __shared__ unsigned short xa[64][136];
  __shared__ unsigned short qh[64][QS];
  __shared__ unsigned short kh[64][QS];
  __shared__ unsigned short vh[64][QS];
  __shared__ unsigned short oh[64][QS];
  int bid = blockIdx.x;
  int ch = bid % 6, v = (bid / 6) % Vv, b = bid / (6 * Vv);
  int t0 = ch * RR;
  int tid = threadIdx.x, lane = tid & 63, w = tid >> 6;

  for (int e = tid; e < 64 * 64; e += 256) {
    int r = e >> 6, cp = e & 63;
    uint32_t u = 0;
    if (r < RR) {
      int xrow = (b * Tt + t0 + r) * Vv + v;
      float m = mean[xrow], rs = rstd[xrow];
      const float* xp = xT + (size_t)xrow * Cc + cp * 2;
      float v0 = (xp[0] - m) * rs * g[cp * 2] + be[cp * 2];
      float v1 = (xp[1] - m) * rs * g[cp * 2 + 1] + be[cp * 2 + 1];
      u = (uint32_t)f2bf(v0) | ((uint32_t)f2bf(v1) << 16);
    }
    *(uint32_t*)&xa[r][cp * 2] = u;
  }
  for (int e = tid; e < (64 - RR) * (QS / 2); e += 256) {
    int r = RR + e / (QS / 2), wd = e % (QS / 2);
    *(uint32_t*)&oh[r][wd * 2] = 0;
  }

  f32x4 acc2[8];
#pragma unroll
  for (int n = 0; n < 8; ++n) acc2[n] = (f32x4){0.f, 0.f, 0.f, 0.f};

  for (int h = 0; h < NH; ++h) {
    __syncthreads();
#pragma unroll
    for (int jj = 0; jj < 12; ++jj) {
      int j = w * 12 + jj;
      int mat = j >> 4, mt = (j >> 2) & 3, ntl = j & 3;
      const unsigned short* bp = (mat == 0) ? wqpk : wkvpk;
      int ntg = (mat == 2 ? 32 : 0) + h * 4 + ntl;
      f32x4 a4 = (f32x4){0.f, 0.f, 0.f, 0.f};
#pragma unroll
      for (int ks = 0; ks < 4; ++ks) {
        bf16x8 af = *(const bf16x8*)&xa[mt * 16 + (lane & 15)][ks * 32 + (lane >> 4) * 8];
        bf16x8 bf_ = *(const bf16x8*)&bp[((size_t)(ntg * 4 + ks) * 64 + lane) * 8];
        a4 = __builtin_amdgcn_mfma_f32_16x16x32_bf16(af, bf_, a4, 0, 0, 0);
      }
      unsigned short* dstp = (mat == 0) ? &qh[0][0] : (mat == 1 ? &kh[0][0] : &vh[0][0]);
#pragma unroll
      for (int i = 0; i < 4; ++i)
        dstp[(mt * 16 + (lane >> 4) * 4 + i) * QS + ntl * 16 + (lane & 15)] = f2bf(a4[i]);
    }
    __syncthreads();
    if (tid < 2 * RR) {
      int r = tid >> 1, half = tid & 1;
      int pbase = (r / 7) * 7;
      float q[32];
#pragma unroll
      for (int c = 0; c < 16; ++c) {
        uint32_t u = *(const uint32_t*)&qh[r][half * 32 + c * 2];
        q[2 * c] = bflo(u); q[2 * c + 1] = bfhi(u);
      }
      float s[Pp];
      float mx = -1e30f;
#pragma unroll
      for (int j = 0; j < Pp; ++j) {
        float acc = 0.f;
#pragma unroll
        for (int c = 0; c < 16; ++c) {
          uint32_t u = *(const uint32_t*)&kh[pbase + j][half * 32 + c * 2];
          acc += q[2 * c] * bflo(u) + q[2 * c + 1] * bfhi(u);
        }
        acc += __shfl_xor(acc, 1);
        s[j] = acc * SCALE;
        mx = fmaxf(mx, s[j]);
      }
      float sum = 0.f;
#pragma unroll
      for (int j = 0; j < Pp; ++j) { s[j] = expf(s[j] - mx); sum += s[j]; }
      float inv = 1.0f / sum;
      float o[32];
#pragma unroll
      for (int c = 0; c < 32; ++c) o[c] = 0.f;
#pragma unroll
      for (int j = 0; j < Pp; ++j) {
        float wgt = s[j] * inv;
#pragma unroll
        for (int c = 0; c < 16; ++c) {
          uint32_t u = *(const uint32_t*)&vh[pbase + j][half * 32 + c * 2];
          o[2 * c] += wgt * bflo(u);
          o[2 * c + 1] += wgt * bfhi(u);
        }
      }
#pragma unroll
      for (int c = 0; c < 16; ++c)
        *(uint32_t*)&oh[r][half * 32 + c * 2] =
            (uint32_t)f2bf(o[2 * c]) | ((uint32_t)f2bf(o[2 * c + 1]) << 16);
    }
    __syncthreads();
#pragma unroll
    for (int ksl = 0; ksl < 2; ++ksl) {
      bf16x8 af = *(const bf16x8*)&oh[w * 16 + (lane & 15)][ksl * 32 + (lane >> 4) * 8];
#pragma unroll
      for (int nn = 0; nn < 8; ++nn) {
        bf16x8 bf_ = *(const bf16x8*)&wopk[((size_t)(nn * 16 + h * 2 + ksl) * 64 + lane) * 8];
        acc2[nn] = __builtin_amdgcn_mfma_f32_16x16x32_bf16(af, bf_, acc2[nn], 0, 0, 0);
      }
    }
  }
#pragma unroll
  for (int nn = 0; nn < 8; ++nn) {
    int col = nn * 16 + (lane & 15);
    float bb = bo[col];
#pragma unroll
    for (int i = 0; i < 4; ++i) {
      int r = w * 16 + (lane >> 4) * 4 + i;
      if (r < RR) {
        int row = (b * Tt + t0 + r) * Vv + v;
        xT[(size_t)row * Cc + col] += bb + acc2[nn][i];
      }
    }
  }
}

// ---------- MFMA fused feed-forward: 32 rows/block ----------
__global__ __launch_bounds__(256) void k_ff_mfma(float* __restrict__ xT,
                                                 const float* __restrict__ mean,
                                                 const float* __restrict__ rstd,
                                                 const float* __restrict__ g,
                                                 const float* __restrict__ be,
                                                 const unsigned short* __restrict__ w1pk,
                                                 const float* __restrict__ b1,
                                                 const unsigned short* __restrict__ w2pk,
                                                 const float* __restrict__ b2) {
  __shared__ unsigned short xa[32][136];
  __shared__ unsigned short hb[32][520];
  int tid = threadIdx.x, lane = tid & 63, w = tid >> 6;
  int row0 = blockIdx.x * 32;

  for (int e = tid; e < 32 * 64; e += 256) {
    int r = e >> 6, cp = e & 63;
    int row = row0 + r;
    float m = mean[row], rs = rstd[row];
    const float* xp = xT + (size_t)row * Cc + cp * 2;
    float v0 = (xp[0] - m) * rs * g[cp * 2] + be[cp * 2];
    float v1 = (xp[1] - m) * rs * g[cp * 2 + 1] + be[cp * 2 + 1];
    uint32_t u = (uint32_t)f2bf(v0) | ((uint32_t)f2bf(v1) << 16);
    *(uint32_t*)&xa[r][cp * 2] = u;
  }
  __syncthreads();

  f32x4 acc[2][8];
#pragma unroll
  for (int m = 0; m < 2; ++m)
#pragma unroll
    for (int n = 0; n < 8; ++n) acc[m][n] = (f32x4){0.f, 0.f, 0.f, 0.f};
#pragma unroll
  for (int ks = 0; ks < 4; ++ks) {
    bf16x8 a0 = *(const bf16x8*)&xa[(lane & 15)][ks * 32 + (lane >> 4) * 8];
    bf16x8 a1 = *(const bf16x8*)&xa[16 + (lane & 15)][ks * 32 + (lane >> 4) * 8];
#pragma unroll
    for (int nn = 0; nn < 8; ++nn) {
      int ntg = w * 8 + nn;
      bf16x8 bf_ = *(const bf16x8*)&w1pk[((size_t)(ntg * 4 + ks) * 64 + lane) * 8];
      acc[0][nn] = __builtin_amdgcn_mfma_f32_16x16x32_bf16(a0, bf_, acc[0][nn], 0, 0, 0);
      acc[1][nn] = __builtin_amdgcn_mfma_f32_16x16x32_bf16(a1, bf_, acc[1][nn], 0, 0, 0);
    }
  }
#pragma unroll
  for (int m = 0; m < 2; ++m)
#pragma unroll
    for (int nn = 0; nn < 8; ++nn) {
      int col = (w * 8 + nn) * 16 + (lane & 15);
      float bb = b1[col];
#pragma unroll
      for (int i = 0; i < 4; ++i) {
        int r = m * 16 + (lane >> 4) * 4 + i;
        float h = acc[m][nn][i] + bb;
        hb[r][col] = f2bf(0.5f * h * (1.0f + erff(h * 0.70710678118654752f)));
      }
    }
  __syncthreads();

  f32x4 acc2[2][2];
#pragma unroll
  for (int m = 0; m < 2; ++m)
#pragma unroll
    for (int n = 0; n < 2; ++n) acc2[m][n] = (f32x4){0.f, 0.f, 0.f, 0.f};
#pragma unroll
  for (int ks = 0; ks < 16; ++ks) {
    bf16x8 a0 = *(const bf16x8*)&hb[(lane & 15)][ks * 32 + (lane >> 4) * 8];
    bf16x8 a1 = *(const bf16x8*)&hb[16 + (lane & 15)][ks * 32 + (lane >> 4) * 8];
#pragma unroll
    for (int nn = 0; nn < 2; ++nn) {
      int ntg = w * 2 + nn;
      bf16x8 bf_ = *(const bf16x8*)&w2pk[((size_t)(ntg * 16 + ks) * 64 + lane) * 8];
      acc2[0][nn] = __builtin_amdgcn_mfma_f32_16x16x32_bf16(a0, bf_, acc2[0][nn], 0, 0, 0);
      acc2[1][nn] = __builtin_amdgcn_mfma_f32_16x16x32_bf16(a1, bf_, acc2[1][nn], 0, 0, 0);
    }
  }
#pragma unroll
  for (int m = 0; m < 2; ++m)
#pragma unroll
    for (int nn = 0; nn < 2; ++nn) {
      int col = (w * 2 + nn) * 16 + (lane & 15);
      float bb = b2[col];
#pragma unroll
      for (int i = 0; i < 4; ++i) {
        int row = row0 + m * 16 + (lane >> 4) * 4 + i;
        xT[(size_t)row * Cc + col] += bb + acc2[m][nn][i];
      }
    }
}

// ---------- MFMA global-attn kv conv: kvg[16800][1024] bf16 ----------
__global__ __launch_bounds__(256) void k_gkv_mfma(const float* __restrict__ xT,
                                                  const float* __restrict__ mean,
                                                  const float* __restrict__ rstd,
                                                  const float* __restrict__ g,
                                                  const float* __restrict__ be,
                                                  const unsigned short* __restrict__ wkvpk,
                                                  unsigned short* __restrict__ kvg) {
  __shared__ unsigned short xa[32][136];
  int tid = threadIdx.x, lane = tid & 63, w = tid >> 6;
  int g0 = blockIdx.x * 32;
  int nh = blockIdx.y;
  f32x4 acc[2][8];
#pragma unroll
  for (int m = 0; m < 2; ++m)
#pragma unroll
    for (int n = 0; n < 8; ++n) acc[m][n] = (f32x4){0.f, 0.f, 0.f, 0.f};

  for (int kk = 0; kk < 7; ++kk) {
    __syncthreads();
    for (int e = tid; e < 32 * 64; e += 256) {
      int r = e >> 6, cp = e & 63;
      int grow = g0 + r;
      int b = grow / (TK * Vv), rem = grow % (TK * Vv), tk = rem / Vv, v = rem % Vv;
      int xrow = (b * Tt + tk * 7 + kk) * Vv + v;
      float m = mean[xrow], rs = rstd[xrow];
      const float* xp = xT + (size_t)xrow * Cc + cp * 2;
      float v0 = (xp[0] - m) * rs * g[cp * 2] + be[cp * 2];
      float v1 = (xp[1] - m) * rs * g[cp * 2 + 1] + be[cp * 2 + 1];
      *(uint32_t*)&xa[r][cp * 2] = (uint32_t)f2bf(v0) | ((uint32_t)f2bf(v1) << 16);
    }
    __syncthreads();
    const unsigned short* bp = wkvpk + kk * 131072;
#pragma unroll
    for (int ks = 0; ks < 4; ++ks) {
      bf16x8 a0 = *(const bf16x8*)&xa[(lane & 15)][ks * 32 + (lane >> 4) * 8];
      bf16x8 a1 = *(const bf16x8*)&xa[16 + (lane & 15)][ks * 32 + (lane >> 4) * 8];
#pragma unroll
      for (int nn = 0; nn < 8; ++nn) {
        int ntg = nh * 32 + w * 8 + nn;
        bf16x8 bf_ = *(const bf16x8*)&bp[((size_t)(ntg * 4 + ks) * 64 + lane) * 8];
        acc[0][nn] = __builtin_amdgcn_mfma_f32_16x16x32_bf16(a0, bf_, acc[0][nn], 0, 0, 0);
        acc[1][nn] = __builtin_amdgcn_mfma_f32_16x16x32_bf16(a1, bf_, acc[1][nn], 0, 0, 0);
      }
    }
  }
#pragma unroll
  for (int m = 0; m < 2; ++m)
#pragma unroll
    for (int nn = 0; nn < 8; ++nn) {
      int col = nh * 512 + (w * 8 + nn) * 16 + (lane & 15);
#pragma unroll
      for (int i = 0; i < 4; ++i) {
        int grow = g0 + m * 16 + (lane >> 4) * 4 + i;
        kvg[(size_t)grow * 1024 + col] = f2bf(acc[m][nn][i]);
      }
    }
}

// ---------- global attention, full-MFMA: per (b, v, 64-row chunk) ----------
// swapped QK^T (S^T = K x Q^T), in-reg softmax via shfl 16/32, PV as O^T = V^T x P,
// per-head projection accumulated in registers (no obuf).
__global__ __launch_bounds__(256) void k_gattn4(float* __restrict__ xT,
                                                const float* __restrict__ mean,
                                                const float* __restrict__ rstd,
                                                const float* __restrict__ g,
                                                const float* __restrict__ be,
                                                const unsigned short* __restrict__ wqpk,
                                                const unsigned short* __restrict__ kvg,
                                                const unsigned short* __restrict__ wopk,
                                                const float* __restrict__ bo) {
  __shared__ unsigned short xa[64][136];   // LN'd x
  __shared__ unsigned short qh[64][72];    // q head slice  [q][d]
  __shared__ unsigned short kh[48][72];    // k head slice  [kv][d], rows 42..47 zero
  __shared__ unsigned short vht[64][72];   // v^T head slice [d][kv], cols 42..63 zero
  __shared__ unsigned short pq[64][72];    // softmax P [q][kv], cols 42..63 zero
  __shared__ unsigned short oh[64][72];    // o head slice [q][d]

  int bid = blockIdx.x;
  int ch = bid % 5, v = (bid / 5) % Vv, b = bid / (5 * Vv);
  int t0 = ch * 64;
  int nR = (Tt - t0 < 64) ? (Tt - t0) : 64;   // 64 or 38
  int tid = threadIdx.x, lane = tid & 63, w = tid >> 6;
  int lc = lane & 15, lg = lane >> 4;

  for (int e = tid; e < 64 * 64; e += 256) {
    int r = e >> 6, cp = e & 63;
    uint32_t u = 0;
    if (r < nR) {
      int xrow = (b * Tt + t0 + r) * Vv + v;
      float m = mean[xrow], rs = rstd[xrow];
      const float* xp = xT + (size_t)xrow * Cc + cp * 2;
      float v0 = (xp[0] - m) * rs * g[cp * 2] + be[cp * 2];
      float v1 = (xp[1] - m) * rs * g[cp * 2 + 1] + be[cp * 2 + 1];
      u = (uint32_t)f2bf(v0) | ((uint32_t)f2bf(v1) << 16);
    }
    *(uint32_t*)&xa[r][cp * 2] = u;
  }
  __syncthreads();

  f32x4 acc2[8];
#pragma unroll
  for (int n = 0; n < 8; ++n) acc2[n] = (f32x4){0.f, 0.f, 0.f, 0.f};

  for (int h = 0; h < NH; ++h) {
    // ---- staging: q-proj MFMA (wave w -> qtile w), K rows, V^T ----
#pragma unroll
    for (int ntl = 0; ntl < 4; ++ntl) {
      f32x4 a4 = (f32x4){0.f, 0.f, 0.f, 0.f};
#pragma unroll
      for (int ks = 0; ks < 4; ++ks) {
        bf16x8 af = *(const bf16x8*)&xa[w * 16 + lc][ks * 32 + lg * 8];
        bf16x8 bf_ = *(const bf16x8*)&wqpk[((size_t)((h * 4 + ntl) * 4 + ks) * 64 + lane) * 8];
        a4 = __builtin_amdgcn_mfma_f32_16x16x32_bf16(af, bf_, a4, 0, 0, 0);
      }
#pragma unroll
      for (int i = 0; i < 4; ++i)
        qh[w * 16 + lg * 4 + i][ntl * 16 + lc] = f2bf(a4[i]);
    }
    for (int e = tid; e < 48 * 32; e += 256) {
      int j = e >> 5, dw = e & 31;
      uint32_t u = 0;
      if (j < TK)
        u = *(const uint32_t*)(kvg + (((size_t)(b * TK + j) * Vv + v) * 1024 + h * 64 + dw * 2));
      *(uint32_t*)&kh[j][dw * 2] = u;
    }
    for (int e = tid; e < 64 * 32; e += 256) {
      int j = e >> 5, dp = e & 31;
      uint32_t u = 0;
      if (j < TK)
        u = *(const uint32_t*)(kvg + (((size_t)(b * TK + j) * Vv + v) * 1024 + 512 + h * 64 + dp * 2));
      vht[dp * 2][j]     = (unsigned short)(u & 0xffffu);
      vht[dp * 2 + 1][j] = (unsigned short)(u >> 16);
    }
    __syncthreads();   // B1

    // ---- S^T = K x Q^T (wave w owns qtile w) ----
    bf16x8 bq0 = *(const bf16x8*)&qh[w * 16 + lc][lg * 8];
    bf16x8 bq1 = *(const bf16x8*)&qh[w * 16 + lc][32 + lg * 8];
    f32x4 st[3];
#pragma unroll
    for (int t = 0; t < 3; ++t) {
      st[t] = (f32x4){0.f, 0.f, 0.f, 0.f};
      bf16x8 ak0 = *(const bf16x8*)&kh[t * 16 + lc][lg * 8];
      bf16x8 ak1 = *(const bf16x8*)&kh[t * 16 + lc][32 + lg * 8];
      st[t] = __builtin_amdgcn_mfma_f32_16x16x32_bf16(ak0, bq0, st[t], 0, 0, 0);
      st[t] = __builtin_amdgcn_mfma_f32_16x16x32_bf16(ak1, bq1, st[t], 0, 0, 0);
    }
    // ---- softmax over kv (per q column = lane lc, spread over lg and regs) ----
    float sv[12];
#pragma unroll
    for (int t = 0; t < 3; ++t)
#pragma unroll
      for (int i = 0; i < 4; ++i) {
        int kv = t * 16 + lg * 4 + i;
        sv[t * 4 + i] = (kv < TK) ? st[t][i] * SCALE : -1e30f;
      }
    float mx = sv[0];
#pragma unroll
    for (int k = 1; k < 12; ++k) mx = fmaxf(mx, sv[k]);
    mx = fmaxf(mx, __shfl_xor(mx, 16));
    mx = fmaxf(mx, __shfl_xor(mx, 32));
    float sum = 0.f;
#pragma unroll
    for (int k = 0; k < 12; ++k) { sv[k] = expf(sv[k] - mx); sum += sv[k]; }
    sum += __shfl_xor(sum, 16);
    sum += __shfl_xor(sum, 32);
    float inv = 1.0f / sum;
#pragma unroll
    for (int t = 0; t < 3; ++t)
#pragma unroll
      for (int i = 0; i < 4; ++i)
        pq[w * 16 + lc][t * 16 + lg * 4 + i] = f2bf(sv[t * 4 + i] * inv);
#pragma unroll
    for (int i = 0; i < 4; ++i)
      pq[w * 16 + lc][48 + lg * 4 + i] = 0;
    __syncthreads();   // B2

    // ---- O^T = V^T x P (wave w owns dtile w) ----
    bf16x8 av0 = *(const bf16x8*)&vht[w * 16 + lc][lg * 8];
    bf16x8 av1 = *(const bf16x8*)&vht[w * 16 + lc][32 + lg * 8];
#pragma unroll
    for (int qt = 0; qt < 4; ++qt) {
      f32x4 ot = (f32x4){0.f, 0.f, 0.f, 0.f};
      bf16x8 bp0 = *(const bf16x8*)&pq[qt * 16 + lc][lg * 8];
      bf16x8 bp1 = *(const bf16x8*)&pq[qt * 16 + lc][32 + lg * 8];
      ot = __builtin_amdgcn_mfma_f32_16x16x32_bf16(av0, bp0, ot, 0, 0, 0);
      ot = __builtin_amdgcn_mfma_f32_16x16x32_bf16(av1, bp1, ot, 0, 0, 0);
#pragma unroll
      for (int i = 0; i < 4; ++i)
        oh[qt * 16 + lc][w * 16 + lg * 4 + i] = f2bf(ot[i]);
    }
    __syncthreads();   // B3

    // ---- proj accumulate (wave w owns m-tile w), K rows h*64..h*64+63 ----
#pragma unroll
    for (int ksl = 0; ksl < 2; ++ksl) {
      bf16x8 af = *(const bf16x8*)&oh[w * 16 + lc][ksl * 32 + lg * 8];
#pragma unroll
      for (int nn = 0; nn < 8; ++nn) {
        bf16x8 bf_ = *(const bf16x8*)&wopk[((size_t)(nn * 16 + h * 2 + ksl) * 64 + lane) * 8];
        acc2[nn] = __builtin_amdgcn_mfma_f32_16x16x32_bf16(af, bf_, acc2[nn], 0, 0, 0);
      }
    }
  }
  // ---- epilogue: bias + residual ----
#pragma unroll
  for (int nn = 0; nn < 8; ++nn) {
    int col = nn * 16 + lc;
    float bb = bo[col];
#pragma unroll
    for (int i = 0; i < 4; ++i) {
      int r = w * 16 + lg * 4 + i;
      if (r < nR) {
        int row = (b * Tt + t0 + r) * Vv + v;
        xT[(size_t)row * Cc + col] += bb + acc2[nn][i];
      }
    }
  }
}

}  // namespace

extern "C" void kernel_launch(void* const* d_in, const int* in_sizes, int n_in,
                              void* d_out, int out_size, void* d_ws, size_t ws_size,
                              hipStream_t stream) {
  const float* x      = (const float*)d_in[0];
  const float* ln1_g  = (const float*)d_in[1];
  const float* ln1_b  = (const float*)d_in[2];
  const float* la_wq  = (const float*)d_in[3];
  const float* la_wkv = (const float*)d_in[4];
  const float* la_wo  = (const float*)d_in[5];
  const float* la_bo  = (const float*)d_in[6];
  const float* ln2_g  = (const float*)d_in[7];
  const float* ln2_b  = (const float*)d_in[8];
  const float* ff1_w1 = (const float*)d_in[9];
  const float* ff1_b1 = (const float*)d_in[10];
  const float* ff1_w2 = (const float*)d_in[11];
  const float* ff1_b2 = (const float*)d_in[12];
  const float* ln3_g  = (const float*)d_in[13];
  const float* ln3_b  = (const float*)d_in[14];
  const float* ga_wq  = (const float*)d_in[15];
  const float* ga_wkv = (const float*)d_in[16];
  const float* ga_wo  = (const float*)d_in[17];
  const float* ga_bo  = (const float*)d_in[18];
  const float* ln4_g  = (const float*)d_in[19];
  const float* ln4_b  = (const float*)d_in[20];
  const float* ff2_w1 = (const float*)d_in[21];
  const float* ff2_b1 = (const float*)d_in[22];
  const float* ff2_w2 = (const float*)d_in[23];
  const float* ff2_b2 = (const float*)d_in[24];

  float* xT   = (float*)d_ws;                          // NPOS*128 f32
  float* mean = xT + (size_t)NPOS * Cc;                // NPOS
  float* rstd = mean + NPOS;                           // NPOS
  unsigned short* obuf = (unsigned short*)(rstd + NPOS);      // (reserved, unused)
  unsigned short* kvg  = obuf + (size_t)NPOS * 512;           // 16800*1024 bf16
  unsigned short* wpk  = kvg + (size_t)NKV * 1024;            // packed weights

  // ---- pack weights ----
  hipLaunchKernelGGL(k_pack, dim3(32 * 4, 1, 2), dim3(64), 0, stream,
                     ff1_w1, wpk + OFF_FF1W1, 4, 512, (size_t)65536, LPK, 0, 0);
  hipLaunchKernelGGL(k_pack, dim3(8 * 16, 1, 2), dim3(64), 0, stream,
                     ff1_w2, wpk + OFF_FF1W2, 16, 128, (size_t)65536, LPK, 0, 0);
  hipLaunchKernelGGL(k_pack, dim3(32 * 4, 1, 2), dim3(64), 0, stream,
                     ff2_w1, wpk + OFF_FF2W1, 4, 512, (size_t)65536, LPK, 0, 0);
  hipLaunchKernelGGL(k_pack, dim3(8 * 16, 1, 2), dim3(64), 0, stream,
                     ff2_w2, wpk + OFF_FF2W2, 16, 128, (size_t)65536, LPK, 0, 0);
  hipLaunchKernelGGL(k_pack, dim3(32 * 4, 1, 2), dim3(64), 0, stream,
                     ga_wq, wpk + OFF_GAWQ, 4, 512, (size_t)65536, LPK, 0, 0);
  hipLaunchKernelGGL(k_pack, dim3(8 * 16, 1, 2), dim3(64), 0, stream,
                     ga_wo, wpk + OFF_GAWO, 16, 128, (size_t)65536, LPK, 0, 0);
  hipLaunchKernelGGL(k_pack, dim3(64 * 4, 7, 2), dim3(64), 0, stream,
                     ga_wkv, wpk + OFF_GAWKV, 4, 7168, (size_t)917504, LPK, 1024, 131072);
  hipLaunchKernelGGL(k_pack, dim3(32 * 4, 1, 2), dim3(64), 0, stream,
                     la_wq, wpk + OFF_LAWQ, 4, 512, (size_t)65536, LPK, 0, 0);
  hipLaunchKernelGGL(k_pack, dim3(64 * 4, 1, 2), dim3(64), 0, stream,
                     la_wkv, wpk + OFF_LAWKV, 4, 1024, (size_t)131072, LPK, 0, 0);
  hipLaunchKernelGGL(k_pack, dim3(8 * 16, 1, 2), dim3(64), 0, stream,
                     la_wo, wpk + OFF_LAWO, 16, 128, (size_t)65536, LPK, 0, 0);

  dim3 blk2(32, 8);
  hipLaunchKernelGGL(k_transpose, dim3((TV + 31) / 32, (Cc + 31) / 32, Bb), blk2, 0, stream,
                     x, xT, Cc, TV);

  for (int i = 0; i < 2; ++i) {
    const unsigned short* lw = wpk + (size_t)i * LPK;

    hipLaunchKernelGGL(k_stats, dim3(NPOS / 4), dim3(256), 0, stream, xT, mean, rstd);
    hipLaunchKernelGGL(k_local_mfma, dim3(Bb * Vv * 6), dim3(256), 0, stream,
                       xT, mean, rstd, ln1_g + i * Cc, ln1_b + i * Cc,
                       lw + OFF_LAWQ, lw + OFF_LAWKV, lw + OFF_LAWO, la_bo + i * Cc);

    hipLaunchKernelGGL(k_stats, dim3(NPOS / 4), dim3(256), 0, stream, xT, mean, rstd);
    hipLaunchKernelGGL(k_ff_mfma, dim3(NPOS / 32), dim3(256), 0, stream,
                       xT, mean, rstd, ln2_g + i * Cc, ln2_b + i * Cc,
                       lw + OFF_FF1W1, ff1_b1 + i * HID, lw + OFF_FF1W2, ff1_b2 + i * Cc);

    hipLaunchKernelGGL(k_stats, dim3(NPOS / 4), dim3(256), 0, stream, xT, mean, rstd);
    hipLaunchKernelGGL(k_gkv_mfma, dim3(NKV / 32, 2), dim3(256), 0, stream,
                       xT, mean, rstd, ln3_g + i * Cc, ln3_b + i * Cc,
                       lw + OFF_GAWKV, kvg);
    hipLaunchKernelGGL(k_gattn4, dim3(Bb * Vv * 5), dim3(256), 0, stream,
                       xT, mean, rstd, ln3_g + i * Cc, ln3_b + i * Cc,
                       lw + OFF_GAWQ, kvg, lw + OFF_GAWO, ga_bo + i * Cc);

    hipLaunchKernelGGL(k_stats, dim3(NPOS / 4), dim3(256), 0, stream, xT, mean, rstd);
    hipLaunchKernelGGL(k_ff_mfma, dim3(NPOS / 32), dim3(256), 0, stream,
                       xT, mean, rstd, ln4_g + i * Cc, ln4_b + i * Cc,
                       lw + OFF_FF2W1, ff2_b1 + i * HID, lw + OFF_FF2W2, ff2_b2 + i * Cc);
  }

  hipLaunchKernelGGL(k_transpose, dim3((Cc + 31) / 32, (TV + 31) / 32, Bb), blk2, 0, stream,
                     xT, (float*)d_out, TV, Cc);
}